// Round 4
// baseline (252.466 us; speedup 1.0000x reference)
//
#include <hip/hip_runtime.h>
#include <hip/hip_bf16.h>

#define ALPHA 0.2f
#define NEGF  -9000000000000000.0f

using short8  = __attribute__((ext_vector_type(8))) short;
using short4v = __attribute__((ext_vector_type(4))) short;
using f32x4   = __attribute__((ext_vector_type(4))) float;

static __device__ __forceinline__ float b2f(short s) {
    union { float f; unsigned u; } v; v.u = ((unsigned)(unsigned short)s) << 16; return v.f;
}
static __device__ __forceinline__ short f2bf(float f) {
    __hip_bfloat16 h = __float2bfloat16(f);
    return *reinterpret_cast<short*>(&h);
}
static __device__ __forceinline__ void gload_lds16(const void* g, void* l) {
    __builtin_amdgcn_global_load_lds(
        (const __attribute__((address_space(1))) unsigned*)g,
        (__attribute__((address_space(3))) unsigned*)l, 16, 0, 0);
}

// ---------------- prep: casts / weight transposes / adjacency bitmask ----------
__global__ void k_cast_x(const float* __restrict__ x, short* __restrict__ xb, int n4) {
    int idx = blockIdx.x * blockDim.x + threadIdx.x;
    if (idx < n4) {
        f32x4 v = ((const f32x4*)x)[idx];
        short4v o;
        o[0] = f2bf(v[0]); o[1] = f2bf(v[1]); o[2] = f2bf(v[2]); o[3] = f2bf(v[3]);
        ((short4v*)xb)[idx] = o;
    }
}

__global__ void k_w1t(const float* __restrict__ W1, short* __restrict__ Wt) {
    int idx = blockIdx.x * blockDim.x + threadIdx.x;
    if (idx < 1024 * 768) {
        int n = idx / 768, k = idx - n * 768;
        int h = n >> 7, o = n & 127;
        Wt[idx] = f2bf(W1[(h * 768 + k) * 128 + o]);
    }
}
__global__ void k_w2t(const float* __restrict__ W2, short* __restrict__ Wt) {
    int idx = blockIdx.x * blockDim.x + threadIdx.x;
    if (idx < 128 * 1024) {
        int n = idx >> 10, k = idx & 1023;
        Wt[idx] = f2bf(W2[k * 128 + n]);
    }
}

// adj int32 (0/1) -> bit-packed: adjb[(b*1024+i)*32 + j/32], bit j%32
__global__ void k_adjbits(const int* __restrict__ adj, unsigned* __restrict__ adjb) {
    int idx = blockIdx.x * blockDim.x + threadIdx.x;   // 8M elements
    int lane = threadIdx.x & 63;
    unsigned long long m = __ballot(adj[idx] > 0);
    if ((lane & 31) == 0) adjb[idx >> 5] = (unsigned)(m >> (lane & 32));
}

// ---------------- bf16 MFMA GEMM (m97-style LDS staged), transposed store ------
// A: MxK row-major bf16.  Bt: NxK row-major bf16.
// store: Ct[((m/1024)*Ncols + n)*1024 + (m%1024)]
__global__ __launch_bounds__(256) void k_gemm_bt(
        const short* __restrict__ A, const short* __restrict__ Bt,
        short* __restrict__ Ct, int K, int Ncols) {
    int tid = threadIdx.x, wave = tid >> 6, lane = tid & 63;
    int lr = lane & 15, lg = lane >> 4;
    int m0 = blockIdx.x * 128, n0 = blockIdx.y * 128;
    int wm = (wave >> 1) * 64, wn = (wave & 1) * 64;
    __shared__ short lsA[2][128 * 32], lsB[2][128 * 32];
    f32x4 acc[4][4];
#pragma unroll
    for (int i = 0; i < 4; i++)
#pragma unroll
        for (int j = 0; j < 4; j++) acc[i][j] = (f32x4){0.f, 0.f, 0.f, 0.f};

    auto stage = [&](int bufsel, int k0) {
#pragma unroll
        for (int s = 0; s < 2; s++) {
            int chunk = s * 256 + tid;          // 0..511 (16B chunks)
            int r = chunk >> 2, c = chunk & 3;
            int csrc = c ^ (r & 3);             // inverse-swizzled source
            int base = (s * 256 + wave * 64) * 8;  // shorts, wave-uniform
            gload_lds16(A + (size_t)(m0 + r) * K + k0 + csrc * 8, &lsA[bufsel][base]);
            gload_lds16(Bt + (size_t)(n0 + r) * K + k0 + csrc * 8, &lsB[bufsel][base]);
        }
    };
    stage(0, 0);
    __syncthreads();
    int buf = 0;
    for (int k0 = 0; k0 < K; k0 += 32) {
        if (k0 + 32 < K) stage(buf ^ 1, k0 + 32);
        short8 a[4], bb[4];
#pragma unroll
        for (int f = 0; f < 4; f++) {
            int ra = wm + f * 16 + lr, rb = wn + f * 16 + lr;
            a[f]  = *(const short8*)(&lsA[buf][ra * 32 + ((lg ^ (ra & 3)) * 8)]);
            bb[f] = *(const short8*)(&lsB[buf][rb * 32 + ((lg ^ (rb & 3)) * 8)]);
        }
#pragma unroll
        for (int fm = 0; fm < 4; fm++)
#pragma unroll
            for (int fn = 0; fn < 4; fn++)
                acc[fm][fn] = __builtin_amdgcn_mfma_f32_16x16x32_bf16(a[fm], bb[fn], acc[fm][fn], 0, 0, 0);
        __syncthreads();
        buf ^= 1;
    }
#pragma unroll
    for (int fm = 0; fm < 4; fm++) {
        int mb = m0 + wm + fm * 16 + lg * 4;
        size_t obase = ((size_t)(mb >> 10) * Ncols) * 1024 + (mb & 1023);
#pragma unroll
        for (int fn = 0; fn < 4; fn++) {
            int n = n0 + wn + fn * 16 + lr;
            short4v st;
            st[0] = f2bf(acc[fm][fn][0]); st[1] = f2bf(acc[fm][fn][1]);
            st[2] = f2bf(acc[fm][fn][2]); st[3] = f2bf(acc[fm][fn][3]);
            *(short4v*)(Ct + obase + (size_t)n * 1024) = st;
        }
    }
}

// ---------------- s1/s2 = h . a1 / h . a2 (reads transposed h: [bh][o][i]) ------
__global__ __launch_bounds__(256) void k_s12(
        const short* __restrict__ ht, const float* __restrict__ a1,
        const float* __restrict__ a2, float* __restrict__ s1,
        float* __restrict__ s2, int nh) {
    int bh = blockIdx.x >> 2;
    int i = ((blockIdx.x & 3) << 8) + threadIdx.x;
    int h = bh % nh;
    const short* base = ht + (size_t)bh * 131072 + i;
    float acc1 = 0.f, acc2 = 0.f;
#pragma unroll 8
    for (int o = 0; o < 128; o++) {
        float v = b2f(base[(size_t)o << 10]);
        acc1 += v * a1[h * 128 + o];
        acc2 += v * a2[h * 128 + o];
    }
    s1[bh * 1024 + i] = acc1;
    s2[bh * 1024 + i] = acc2;
}

// ---------------- per-row softmax stats: c1 = -max - log(sum) ----------------
__global__ __launch_bounds__(256) void k_stats(
        const unsigned* __restrict__ adjb, const float* __restrict__ s1,
        const float* __restrict__ s2, float* __restrict__ c1a, int nh) {
    int w = blockIdx.x * 4 + (threadIdx.x >> 6);
    int lane = threadIdx.x & 63;
    int b = w >> 10, i = w & 1023;
    const unsigned long long* ab =
        (const unsigned long long*)(adjb + ((size_t)(b << 10) + i) * 32);
    unsigned long long aw[16];
#pragma unroll
    for (int jc = 0; jc < 16; jc++) aw[jc] = ab[jc];
    for (int h = 0; h < nh; h++) {
        int bh = b * nh + h;
        float s1i = s1[bh * 1024 + i];
        const float* s2r = s2 + bh * 1024;
        float e[16];
        float m = -3.4e38f;
#pragma unroll
        for (int jc = 0; jc < 16; jc++) {
            float ee = s1i + s2r[jc * 64 + lane];
            ee = fmaxf(ee, ALPHA * ee);
            ee = ((aw[jc] >> lane) & 1) ? ee : NEGF;
            e[jc] = ee;
            m = fmaxf(m, ee);
        }
#pragma unroll
        for (int off = 32; off > 0; off >>= 1) m = fmaxf(m, __shfl_xor(m, off));
        float s = 0.f;
#pragma unroll
        for (int jc = 0; jc < 16; jc++) s += __expf(e[jc] - m);
#pragma unroll
        for (int off = 32; off > 0; off >>= 1) s += __shfl_xor(s, off);
        if (lane == 0) c1a[bh * 1024 + i] = -m - __logf(s);
    }
}

// ---------------- GAT layer-1 attention apply: hp^T = h_t @ p^T, ELU, bf16 -----
__global__ __launch_bounds__(256) void k_attn1(
        const short* __restrict__ ht, const unsigned* __restrict__ adjb,
        const float* __restrict__ s1, const float* __restrict__ s2,
        const float* __restrict__ c1a, short* __restrict__ out) {
    int bh = blockIdx.y;
    int b = bh >> 3, h = bh & 7;
    int tid = threadIdx.x, wave = tid >> 6, lane = tid & 63;
    int lr = lane & 15, lg = lane >> 4;
    int ic = blockIdx.x * 64 + wave * 16 + lr;
    int row = bh * 1024 + ic;
    float s1i = s1[row], c1i = c1a[row];
    const unsigned long long* abrow =
        (const unsigned long long*)(adjb + ((size_t)(b << 10) + ic) * 32);
    const float* s2r = s2 + bh * 1024;
    const short* hbase = ht + (size_t)bh * 131072;

    __shared__ short lsh[2][8192];   // [128 o][64 j] bf16, chunk-XOR swizzled
    f32x4 acc[8];
#pragma unroll
    for (int f = 0; f < 8; f++) acc[f] = (f32x4){0.f, 0.f, 0.f, 0.f};

    auto stage = [&](int bufsel, int j0) {
#pragma unroll
        for (int s = 0; s < 4; s++) {
            int chunk = s * 256 + tid;       // 0..1023 (16B chunks)
            int r = chunk >> 3, c = chunk & 7;
            int csrc = c ^ (r & 7);          // inverse-swizzle the SOURCE (rule 21)
            gload_lds16(hbase + (size_t)r * 1024 + j0 + csrc * 8,
                        &lsh[bufsel][(s * 256 + wave * 64) * 8]);
        }
    };
    stage(0, 0);
    __syncthreads();
    int buf = 0;
    for (int j0 = 0; j0 < 1024; j0 += 64) {
        if (j0 < 960) stage(buf ^ 1, j0 + 64);
        unsigned long long aw = abrow[j0 >> 6];
#pragma unroll
        for (int kk = 0; kk < 2; kk++) {
            int jb = j0 + kk * 32 + lg * 8;
            f32x4 t0 = *(const f32x4*)(s2r + jb);
            f32x4 t1 = *(const f32x4*)(s2r + jb + 4);
            unsigned bits = (unsigned)(aw >> (kk * 32 + lg * 8)) & 0xFFu;
            short8 pb;
#pragma unroll
            for (int e = 0; e < 8; e++) {
                float sv = e < 4 ? t0[e] : t1[e & 3];
                float ee = s1i + sv;
                ee = fmaxf(ee, ALPHA * ee);
                float p = __expf(ee + c1i);
                p = ((bits >> e) & 1) ? p : 0.f;
                pb[e] = f2bf(p);
            }
#pragma unroll
            for (int fm = 0; fm < 8; fm++) {
                int r = fm * 16 + lr;
                int ck = (kk * 4 + lg) ^ (r & 7);   // swizzled read
                short8 af = *(const short8*)(&lsh[buf][r * 64 + ck * 8]);
                acc[fm] = __builtin_amdgcn_mfma_f32_16x16x32_bf16(af, pb, acc[fm], 0, 0, 0);
            }
        }
        __syncthreads();
        buf ^= 1;
    }
    size_t orow = ((size_t)(b << 10) + ic) * 1024 + h * 128;
#pragma unroll
    for (int fm = 0; fm < 8; fm++) {
        int ob = (fm << 4) + lg * 4;
        short4v st;
#pragma unroll
        for (int r = 0; r < 4; r++) {
            float x = acc[fm][r];
            x = x > 0.f ? x : expm1f(x);
            st[r] = f2bf(x);
        }
        *(short4v*)(out + orow + ob) = st;
    }
}

// ---------------- layer-2 attention, GATHERED rows only (33 per batch) ---------
// Computes stats + attention + ELU for rows [node0, ctx[0..31]] -> ghat[b][48][128]
__global__ __launch_bounds__(256) void k_attn2g(
        const short* __restrict__ h2t, const unsigned* __restrict__ adjb,
        const float* __restrict__ s1, const float* __restrict__ s2,
        const int* __restrict__ cidx, float* __restrict__ ghat) {
    int tile = blockIdx.x;      // 0..2
    int b = blockIdx.y;         // 0..7
    int tid = threadIdx.x, wave = tid >> 6, lane = tid & 63;
    int lr = lane & 15, lg = lane >> 4;

    __shared__ int nodes[16];
    __shared__ float sc1[16];
    __shared__ float sacc[4][16][129];

    if (tid < 16) {
        int pos = tile * 16 + tid;
        int nd = 0;
        if (pos >= 1 && pos <= 32) nd = cidx[b * 32 + pos - 1];
        nodes[tid] = nd;
    }
    __syncthreads();

    const float* s2r = s2 + b * 1024;
    // stats: wave w handles rows w*4 .. w*4+3
    for (int q = 0; q < 4; q++) {
        int li = wave * 4 + q;
        int nd = nodes[li];
        float s1i = s1[b * 1024 + nd];
        const unsigned long long* ab =
            (const unsigned long long*)(adjb + ((size_t)(b << 10) + nd) * 32);
        float ev[16];
        float m = -3.4e38f;
#pragma unroll
        for (int c = 0; c < 16; c++) {
            float ee = s1i + s2r[c * 64 + lane];
            ee = fmaxf(ee, ALPHA * ee);
            ee = ((ab[c] >> lane) & 1) ? ee : NEGF;
            ev[c] = ee;
            m = fmaxf(m, ee);
        }
#pragma unroll
        for (int off = 32; off > 0; off >>= 1) m = fmaxf(m, __shfl_xor(m, off));
        float s = 0.f;
#pragma unroll
        for (int c = 0; c < 16; c++) s += __expf(ev[c] - m);
#pragma unroll
        for (int off = 32; off > 0; off >>= 1) s += __shfl_xor(s, off);
        if (lane == 0) sc1[li] = -m - __logf(s);
    }
    __syncthreads();

    // attention over this wave's j-quarter
    int nd = nodes[lr];
    float s1i = s1[b * 1024 + nd];
    float c1i = sc1[lr];
    const unsigned long long* abrow =
        (const unsigned long long*)(adjb + ((size_t)(b << 10) + nd) * 32);
    const short* hb = h2t + (size_t)b * 131072;
    f32x4 acc[8];
#pragma unroll
    for (int f = 0; f < 8; f++) acc[f] = (f32x4){0.f, 0.f, 0.f, 0.f};

    for (int j0 = wave * 256; j0 < wave * 256 + 256; j0 += 32) {
        int jb = j0 + lg * 8;
        f32x4 t0 = *(const f32x4*)(s2r + jb);
        f32x4 t1 = *(const f32x4*)(s2r + jb + 4);
        unsigned bits = (unsigned)(abrow[j0 >> 6] >> ((j0 & 32) + lg * 8)) & 0xFFu;
        short8 pb;
#pragma unroll
        for (int e = 0; e < 8; e++) {
            float sv = e < 4 ? t0[e] : t1[e & 3];
            float ee = s1i + sv;
            ee = fmaxf(ee, ALPHA * ee);
            float p = __expf(ee + c1i);
            p = ((bits >> e) & 1) ? p : 0.f;
            pb[e] = f2bf(p);
        }
#pragma unroll
        for (int fm = 0; fm < 8; fm++) {
            short8 af = *(const short8*)(hb + (size_t)(fm * 16 + lr) * 1024 + jb);
            acc[fm] = __builtin_amdgcn_mfma_f32_16x16x32_bf16(af, pb, acc[fm], 0, 0, 0);
        }
    }
    // per-wave partials -> LDS
#pragma unroll
    for (int fm = 0; fm < 8; fm++)
#pragma unroll
        for (int r = 0; r < 4; r++)
            sacc[wave][lr][fm * 16 + lg * 4 + r] = acc[fm][r];
    __syncthreads();
    // reduce 4 waves + ELU + store
    for (int e = tid; e < 2048; e += 256) {
        int li = e >> 7, o = e & 127;
        float v = sacc[0][li][o] + sacc[1][li][o] + sacc[2][li][o] + sacc[3][li][o];
        v = v > 0.f ? v : expm1f(v);
        ghat[((size_t)b * 48 + tile * 16 + li) * 128 + o] = v;
    }
}

// ---------------- tail: MHA + proj + LN + relu + proj (reads gathered rows) ----
__global__ __launch_bounds__(256) void k_final(
        const float* __restrict__ ghat,
        const float* __restrict__ wq, const float* __restrict__ bq,
        const float* __restrict__ wk, const float* __restrict__ bk,
        const float* __restrict__ wv, const float* __restrict__ bv,
        const float* __restrict__ wo, const float* __restrict__ bo,
        const float* __restrict__ p1w, const float* __restrict__ p1b,
        const float* __restrict__ lng, const float* __restrict__ lnb,
        const float* __restrict__ p2w, const float* __restrict__ p2b,
        float* __restrict__ out) {
    int b = blockIdx.x, t = threadIdx.x;
    __shared__ float sq[128], sctx[32][128], sK[32][128], sV[32][128];
    __shared__ float sQ[128], sP[4][32], sO[128], sT[128], sZ[128];
    __shared__ float sred[2];

    if (t < 128) sq[t] = ghat[(size_t)b * 48 * 128 + t];
    for (int e = t; e < 4096; e += 256) {
        int r = e >> 7, c = e & 127;
        sctx[r][c] = ghat[((size_t)b * 48 + 1 + r) * 128 + c];
    }
    __syncthreads();
    if (t < 128) {
        float accq = bq[t];
        for (int c = 0; c < 128; c++) accq += sq[c] * wq[c * 128 + t];
        sQ[t] = accq;
    }
    for (int e = t; e < 4096; e += 256) {
        int r = e >> 7, o = e & 127;
        float ak = bk[o], av_ = bv[o];
        for (int c = 0; c < 128; c++) {
            float x = sctx[r][c];
            ak += x * wk[c * 128 + o];
            av_ += x * wv[c * 128 + o];
        }
        sK[r][o] = ak; sV[r][o] = av_;
    }
    __syncthreads();
    if (t < 128) {
        int hh = t >> 5, j = t & 31;
        float s = 0.f;
        for (int d = 0; d < 32; d++) s += sQ[hh * 32 + d] * sK[j][hh * 32 + d];
        sP[hh][j] = s * 0.17677669529663687f;
    }
    __syncthreads();
    if (t < 4) {
        float m = -3.4e38f;
        for (int j = 0; j < 32; j++) m = fmaxf(m, sP[t][j]);
        float s = 0.f;
        for (int j = 0; j < 32; j++) { float p = __expf(sP[t][j] - m); sP[t][j] = p; s += p; }
        float r = 1.f / s;
        for (int j = 0; j < 32; j++) sP[t][j] *= r;
    }
    __syncthreads();
    if (t < 128) {
        int hh = t >> 5;
        float s = 0.f;
        for (int j = 0; j < 32; j++) s += sP[hh][j] * sV[j][t];
        sO[t] = s;
    }
    __syncthreads();
    if (t < 128) {
        float s = bo[t];
        for (int o = 0; o < 128; o++) s += sO[o] * wo[o * 128 + t];
        sT[t] = s;
    }
    __syncthreads();
    if (t < 128) {
        float s = p1b[t];
        for (int c = 0; c < 128; c++) s += sT[c] * p1w[c * 128 + t];
        sZ[t] = s;
    }
    __syncthreads();
    if (t < 64) {
        float v = sZ[t] + sZ[t + 64];
        for (int off = 32; off > 0; off >>= 1) v += __shfl_xor(v, off);
        if (t == 0) sred[0] = v * (1.f / 128.f);
    }
    __syncthreads();
    float mu = sred[0];
    if (t < 64) {
        float d1 = sZ[t] - mu, d2 = sZ[t + 64] - mu;
        float v = d1 * d1 + d2 * d2;
        for (int off = 32; off > 0; off >>= 1) v += __shfl_xor(v, off);
        if (t == 0) sred[1] = v * (1.f / 128.f);
    }
    __syncthreads();
    float rstd = rsqrtf(sred[1] + 1e-5f);
    if (t < 128) {
        float z = (sZ[t] - mu) * rstd * lng[t] + lnb[t];
        sT[t] = fmaxf(z, 0.f);
    }
    __syncthreads();
    for (int j = t; j < 768; j += 256) {
        float s = p2b[j];
        for (int o = 0; o < 128; o++) s += sT[o] * p2w[o * 768 + j];
        out[b * 768 + j] = s;
    }
}

extern "C" void kernel_launch(void* const* d_in, const int* in_sizes, int n_in,
                              void* d_out, int out_size, void* d_ws, size_t ws_size,
                              hipStream_t stream) {
    const float* x   = (const float*)d_in[0];
    const int*  adj  = (const int*)d_in[1];
    const int*  cidx = (const int*)d_in[2];
    const float* W1  = (const float*)d_in[3];
    const float* a11 = (const float*)d_in[4];
    const float* a21 = (const float*)d_in[5];
    const float* W2  = (const float*)d_in[6];
    const float* a12 = (const float*)d_in[7];
    const float* a22 = (const float*)d_in[8];
    const float* wq = (const float*)d_in[9];  const float* bq = (const float*)d_in[10];
    const float* wk = (const float*)d_in[11]; const float* bk = (const float*)d_in[12];
    const float* wv = (const float*)d_in[13]; const float* bv = (const float*)d_in[14];
    const float* wo = (const float*)d_in[15]; const float* bo = (const float*)d_in[16];
    const float* p1w = (const float*)d_in[17]; const float* p1b = (const float*)d_in[18];
    const float* lng = (const float*)d_in[19]; const float* lnb = (const float*)d_in[20];
    const float* p2w = (const float*)d_in[21]; const float* p2b = (const float*)d_in[22];
    float* out = (float*)d_out;

    char* ws = (char*)d_ws;
    size_t off = 0;
    auto alloc = [&](size_t bytes) -> char* {
        char* p = ws + off;
        off = (off + bytes + 255) & ~(size_t)255;
        return p;
    };
    short* Xb   = (short*)alloc(8192ull * 768 * 2);
    short* W1T  = (short*)alloc(1024ull * 768 * 2);
    short* W2T  = (short*)alloc(128ull * 1024 * 2);
    unsigned* adjb = (unsigned*)alloc(8ull * 1024 * 32 * 4);
    short* h1t  = (short*)alloc(64ull * 128 * 1024 * 2);
    float* s1a  = (float*)alloc(64ull * 1024 * 4);
    float* s2a  = (float*)alloc(64ull * 1024 * 4);
    float* c1a  = (float*)alloc(64ull * 1024 * 4);
    short* hcat = (short*)alloc(8192ull * 1024 * 2);
    short* h2t  = (short*)alloc(8ull * 128 * 1024 * 2);
    float* s1b  = (float*)alloc(8192ull * 4);
    float* s2b  = (float*)alloc(8192ull * 4);
    float* ghat = (float*)alloc(8ull * 48 * 128 * 4);
    if (off > ws_size) return;

    k_cast_x<<<6144, 256, 0, stream>>>(x, Xb, 1572864);
    k_w1t<<<3072, 256, 0, stream>>>(W1, W1T);
    k_w2t<<<512, 256, 0, stream>>>(W2, W2T);
    k_adjbits<<<32768, 256, 0, stream>>>(adj, adjb);

    // layer 1
    k_gemm_bt<<<dim3(64, 8), 256, 0, stream>>>(Xb, W1T, h1t, 768, 1024);
    k_s12<<<256, 256, 0, stream>>>(h1t, a11, a21, s1a, s2a, 8);
    k_stats<<<2048, 256, 0, stream>>>(adjb, s1a, s2a, c1a, 8);
    k_attn1<<<dim3(16, 64), 256, 0, stream>>>(h1t, adjb, s1a, s2a, c1a, hcat);

    // layer 2 (GEMM full; attention only for gathered rows)
    k_gemm_bt<<<dim3(64, 1), 256, 0, stream>>>(hcat, W2T, h2t, 1024, 128);
    k_s12<<<32, 256, 0, stream>>>(h2t, a12, a22, s1b, s2b, 1);
    k_attn2g<<<dim3(3, 8), 256, 0, stream>>>(h2t, adjb, s1b, s2b, cidx, ghat);

    // tail
    k_final<<<8, 256, 0, stream>>>(ghat, wq, bq, wk, bk, wv, bv, wo, bo,
                                   p1w, p1b, lng, lnb, p2w, p2b, out);
}

// Round 5
// 237.192 us; speedup vs baseline: 1.0644x; 1.0644x over previous
//
#include <hip/hip_runtime.h>
#include <hip/hip_bf16.h>

#define ALPHA 0.2f
#define NEGF  -9000000000000000.0f

using short8  = __attribute__((ext_vector_type(8))) short;
using short4v = __attribute__((ext_vector_type(4))) short;
using f32x4   = __attribute__((ext_vector_type(4))) float;

static __device__ __forceinline__ float b2f(short s) {
    union { float f; unsigned u; } v; v.u = ((unsigned)(unsigned short)s) << 16; return v.f;
}
static __device__ __forceinline__ short f2bf(float f) {
    __hip_bfloat16 h = __float2bfloat16(f);
    return *reinterpret_cast<short*>(&h);
}
static __device__ __forceinline__ void gload_lds16(const void* g, void* l) {
    __builtin_amdgcn_global_load_lds(
        (const __attribute__((address_space(1))) unsigned*)g,
        (__attribute__((address_space(3))) unsigned*)l, 16, 0, 0);
}

// ---------------- prep: casts / weight transposes / adjacency bitmask ----------
__global__ void k_cast_x(const float* __restrict__ x, short* __restrict__ xb, int n4) {
    int idx = blockIdx.x * blockDim.x + threadIdx.x;
    if (idx < n4) {
        f32x4 v = ((const f32x4*)x)[idx];
        short4v o;
        o[0] = f2bf(v[0]); o[1] = f2bf(v[1]); o[2] = f2bf(v[2]); o[3] = f2bf(v[3]);
        ((short4v*)xb)[idx] = o;
    }
}

__global__ void k_w1t(const float* __restrict__ W1, short* __restrict__ Wt) {
    int idx = blockIdx.x * blockDim.x + threadIdx.x;
    if (idx < 1024 * 768) {
        int n = idx / 768, k = idx - n * 768;
        int h = n >> 7, o = n & 127;
        Wt[idx] = f2bf(W1[(h * 768 + k) * 128 + o]);
    }
}
__global__ void k_w2t(const float* __restrict__ W2, short* __restrict__ Wt) {
    int idx = blockIdx.x * blockDim.x + threadIdx.x;
    if (idx < 128 * 1024) {
        int n = idx >> 10, k = idx & 1023;
        Wt[idx] = f2bf(W2[k * 128 + n]);
    }
}

// adj int32 (0/1) -> bit-packed: adjb[(b*1024+i)*32 + j/32], bit j%32
__global__ void k_adjbits(const int* __restrict__ adj, unsigned* __restrict__ adjb) {
    int idx = blockIdx.x * blockDim.x + threadIdx.x;   // 8M elements
    int lane = threadIdx.x & 63;
    unsigned long long m = __ballot(adj[idx] > 0);
    if ((lane & 31) == 0) adjb[idx >> 5] = (unsigned)(m >> (lane & 32));
}

// ---------------- bf16 MFMA GEMM (LDS staged, dbuf, swizzled), transposed store -
__global__ __launch_bounds__(256) void k_gemm_bt(
        const short* __restrict__ A, const short* __restrict__ Bt,
        short* __restrict__ Ct, int K, int Ncols) {
    int tid = threadIdx.x, wave = tid >> 6, lane = tid & 63;
    int lr = lane & 15, lg = lane >> 4;
    int m0 = blockIdx.x * 128, n0 = blockIdx.y * 128;
    int wm = (wave >> 1) * 64, wn = (wave & 1) * 64;
    __shared__ short lsA[2][128 * 32], lsB[2][128 * 32];
    f32x4 acc[4][4];
#pragma unroll
    for (int i = 0; i < 4; i++)
#pragma unroll
        for (int j = 0; j < 4; j++) acc[i][j] = (f32x4){0.f, 0.f, 0.f, 0.f};

    auto stage = [&](int bufsel, int k0) {
#pragma unroll
        for (int s = 0; s < 2; s++) {
            int chunk = s * 256 + tid;          // 0..511 (16B chunks)
            int r = chunk >> 2, c = chunk & 3;
            int csrc = c ^ (r & 3);             // inverse-swizzled source
            int base = (s * 256 + wave * 64) * 8;  // shorts, wave-uniform
            gload_lds16(A + (size_t)(m0 + r) * K + k0 + csrc * 8, &lsA[bufsel][base]);
            gload_lds16(Bt + (size_t)(n0 + r) * K + k0 + csrc * 8, &lsB[bufsel][base]);
        }
    };
    stage(0, 0);
    __syncthreads();
    int buf = 0;
    for (int k0 = 0; k0 < K; k0 += 32) {
        if (k0 + 32 < K) stage(buf ^ 1, k0 + 32);
        short8 a[4], bb[4];
#pragma unroll
        for (int f = 0; f < 4; f++) {
            int ra = wm + f * 16 + lr, rb = wn + f * 16 + lr;
            a[f]  = *(const short8*)(&lsA[buf][ra * 32 + ((lg ^ (ra & 3)) * 8)]);
            bb[f] = *(const short8*)(&lsB[buf][rb * 32 + ((lg ^ (rb & 3)) * 8)]);
        }
#pragma unroll
        for (int fm = 0; fm < 4; fm++)
#pragma unroll
            for (int fn = 0; fn < 4; fn++)
                acc[fm][fn] = __builtin_amdgcn_mfma_f32_16x16x32_bf16(a[fm], bb[fn], acc[fm][fn], 0, 0, 0);
        __syncthreads();
        buf ^= 1;
    }
#pragma unroll
    for (int fm = 0; fm < 4; fm++) {
        int mb = m0 + wm + fm * 16 + lg * 4;
        size_t obase = ((size_t)(mb >> 10) * Ncols) * 1024 + (mb & 1023);
#pragma unroll
        for (int fn = 0; fn < 4; fn++) {
            int n = n0 + wn + fn * 16 + lr;
            short4v st;
            st[0] = f2bf(acc[fm][fn][0]); st[1] = f2bf(acc[fm][fn][1]);
            st[2] = f2bf(acc[fm][fn][2]); st[3] = f2bf(acc[fm][fn][3]);
            *(short4v*)(Ct + obase + (size_t)n * 1024) = st;
        }
    }
}

// ---------------- s1/s2 = h . a1 / h . a2 (reads transposed h: [bh][o][i]) ------
__global__ __launch_bounds__(256) void k_s12(
        const short* __restrict__ ht, const float* __restrict__ a1,
        const float* __restrict__ a2, float* __restrict__ s1,
        float* __restrict__ s2, int nh) {
    int bh = blockIdx.x >> 2;
    int i = ((blockIdx.x & 3) << 8) + threadIdx.x;
    int h = bh % nh;
    const short* base = ht + (size_t)bh * 131072 + i;
    float acc1 = 0.f, acc2 = 0.f;
#pragma unroll 8
    for (int o = 0; o < 128; o++) {
        float v = b2f(base[(size_t)o << 10]);
        acc1 += v * a1[h * 128 + o];
        acc2 += v * a2[h * 128 + o];
    }
    s1[bh * 1024 + i] = acc1;
    s2[bh * 1024 + i] = acc2;
}

// ---------------- per-row softmax stats: c1 = -max - log(sum) ----------------
__global__ __launch_bounds__(256) void k_stats(
        const unsigned* __restrict__ adjb, const float* __restrict__ s1,
        const float* __restrict__ s2, float* __restrict__ c1a, int nh) {
    int w = blockIdx.x * 4 + (threadIdx.x >> 6);
    int lane = threadIdx.x & 63;
    int b = w >> 10, i = w & 1023;
    const unsigned long long* ab =
        (const unsigned long long*)(adjb + ((size_t)(b << 10) + i) * 32);
    unsigned long long aw[16];
#pragma unroll
    for (int jc = 0; jc < 16; jc++) aw[jc] = ab[jc];
    for (int h = 0; h < nh; h++) {
        int bh = b * nh + h;
        float s1i = s1[bh * 1024 + i];
        const float* s2r = s2 + bh * 1024;
        float e[16];
        float m = -3.4e38f;
#pragma unroll
        for (int jc = 0; jc < 16; jc++) {
            float ee = s1i + s2r[jc * 64 + lane];
            ee = fmaxf(ee, ALPHA * ee);
            ee = ((aw[jc] >> lane) & 1) ? ee : NEGF;
            e[jc] = ee;
            m = fmaxf(m, ee);
        }
#pragma unroll
        for (int off = 32; off > 0; off >>= 1) m = fmaxf(m, __shfl_xor(m, off));
        float s = 0.f;
#pragma unroll
        for (int jc = 0; jc < 16; jc++) s += __expf(e[jc] - m);
#pragma unroll
        for (int off = 32; off > 0; off >>= 1) s += __shfl_xor(s, off);
        if (lane == 0) c1a[bh * 1024 + i] = -m - __logf(s);
    }
}

// ---------------- GAT layer-1 attention apply: hp^T = h_t @ p^T, ELU, bf16 -----
__global__ __launch_bounds__(256) void k_attn1(
        const short* __restrict__ ht, const unsigned* __restrict__ adjb,
        const float* __restrict__ s1, const float* __restrict__ s2,
        const float* __restrict__ c1a, short* __restrict__ out) {
    int bh = blockIdx.y;
    int b = bh >> 3, h = bh & 7;
    int tid = threadIdx.x, wave = tid >> 6, lane = tid & 63;
    int lr = lane & 15, lg = lane >> 4;
    int ic = blockIdx.x * 64 + wave * 16 + lr;
    int row = bh * 1024 + ic;
    float s1i = s1[row], c1i = c1a[row];
    const unsigned long long* abrow =
        (const unsigned long long*)(adjb + ((size_t)(b << 10) + ic) * 32);
    const float* s2r = s2 + bh * 1024;
    const short* hbase = ht + (size_t)bh * 131072;

    __shared__ short lsh[2][8192];   // [128 o][64 j] bf16, chunk-XOR swizzled
    f32x4 acc[8];
#pragma unroll
    for (int f = 0; f < 8; f++) acc[f] = (f32x4){0.f, 0.f, 0.f, 0.f};

    auto stage = [&](int bufsel, int j0) {
#pragma unroll
        for (int s = 0; s < 4; s++) {
            int chunk = s * 256 + tid;       // 0..1023 (16B chunks)
            int r = chunk >> 3, c = chunk & 7;
            int csrc = c ^ (r & 7);          // inverse-swizzle the SOURCE (rule 21)
            gload_lds16(hbase + (size_t)r * 1024 + j0 + csrc * 8,
                        &lsh[bufsel][(s * 256 + wave * 64) * 8]);
        }
    };
    stage(0, 0);
    __syncthreads();
    int buf = 0;
    for (int j0 = 0; j0 < 1024; j0 += 64) {
        if (j0 < 960) stage(buf ^ 1, j0 + 64);
        unsigned long long aw = abrow[j0 >> 6];
#pragma unroll
        for (int kk = 0; kk < 2; kk++) {
            int jb = j0 + kk * 32 + lg * 8;
            f32x4 t0 = *(const f32x4*)(s2r + jb);
            f32x4 t1 = *(const f32x4*)(s2r + jb + 4);
            unsigned bits = (unsigned)(aw >> (kk * 32 + lg * 8)) & 0xFFu;
            short8 pb;
#pragma unroll
            for (int e = 0; e < 8; e++) {
                float sv = e < 4 ? t0[e] : t1[e & 3];
                float ee = s1i + sv;
                ee = fmaxf(ee, ALPHA * ee);
                float p = __expf(ee + c1i);
                p = ((bits >> e) & 1) ? p : 0.f;
                pb[e] = f2bf(p);
            }
#pragma unroll
            for (int fm = 0; fm < 8; fm++) {
                int r = fm * 16 + lr;
                int ck = (kk * 4 + lg) ^ (r & 7);   // swizzled read
                short8 af = *(const short8*)(&lsh[buf][r * 64 + ck * 8]);
                acc[fm] = __builtin_amdgcn_mfma_f32_16x16x32_bf16(af, pb, acc[fm], 0, 0, 0);
            }
        }
        __syncthreads();
        buf ^= 1;
    }
    size_t orow = ((size_t)(b << 10) + ic) * 1024 + h * 128;
#pragma unroll
    for (int fm = 0; fm < 8; fm++) {
        int ob = (fm << 4) + lg * 4;
        short4v st;
#pragma unroll
        for (int r = 0; r < 4; r++) {
            float x = acc[fm][r];
            x = x > 0.f ? x : expm1f(x);
            st[r] = f2bf(x);
        }
        *(short4v*)(out + orow + ob) = st;
    }
}

// ---------------- layer-2 attention, GATHERED rows only (33 per batch) ---------
__global__ __launch_bounds__(256) void k_attn2g(
        const short* __restrict__ h2t, const unsigned* __restrict__ adjb,
        const float* __restrict__ s1, const float* __restrict__ s2,
        const int* __restrict__ cidx, float* __restrict__ ghat) {
    int tile = blockIdx.x;      // 0..2
    int b = blockIdx.y;         // 0..7
    int tid = threadIdx.x, wave = tid >> 6, lane = tid & 63;
    int lr = lane & 15, lg = lane >> 4;

    __shared__ int nodes[16];
    __shared__ float sc1[16];
    __shared__ float sacc[4][16][129];

    if (tid < 16) {
        int pos = tile * 16 + tid;
        int nd = 0;
        if (pos >= 1 && pos <= 32) nd = cidx[b * 32 + pos - 1];
        nodes[tid] = nd;
    }
    __syncthreads();

    const float* s2r = s2 + b * 1024;
    for (int q = 0; q < 4; q++) {
        int li = wave * 4 + q;
        int nd = nodes[li];
        float s1i = s1[b * 1024 + nd];
        const unsigned long long* ab =
            (const unsigned long long*)(adjb + ((size_t)(b << 10) + nd) * 32);
        float ev[16];
        float m = -3.4e38f;
#pragma unroll
        for (int c = 0; c < 16; c++) {
            float ee = s1i + s2r[c * 64 + lane];
            ee = fmaxf(ee, ALPHA * ee);
            ee = ((ab[c] >> lane) & 1) ? ee : NEGF;
            ev[c] = ee;
            m = fmaxf(m, ee);
        }
#pragma unroll
        for (int off = 32; off > 0; off >>= 1) m = fmaxf(m, __shfl_xor(m, off));
        float s = 0.f;
#pragma unroll
        for (int c = 0; c < 16; c++) s += __expf(ev[c] - m);
#pragma unroll
        for (int off = 32; off > 0; off >>= 1) s += __shfl_xor(s, off);
        if (lane == 0) sc1[li] = -m - __logf(s);
    }
    __syncthreads();

    int nd = nodes[lr];
    float s1i = s1[b * 1024 + nd];
    float c1i = sc1[lr];
    const unsigned long long* abrow =
        (const unsigned long long*)(adjb + ((size_t)(b << 10) + nd) * 32);
    const short* hb = h2t + (size_t)b * 131072;
    f32x4 acc[8];
#pragma unroll
    for (int f = 0; f < 8; f++) acc[f] = (f32x4){0.f, 0.f, 0.f, 0.f};

    for (int j0 = wave * 256; j0 < wave * 256 + 256; j0 += 32) {
        int jb = j0 + lg * 8;
        f32x4 t0 = *(const f32x4*)(s2r + jb);
        f32x4 t1 = *(const f32x4*)(s2r + jb + 4);
        unsigned bits = (unsigned)(abrow[j0 >> 6] >> ((j0 & 32) + lg * 8)) & 0xFFu;
        short8 pb;
#pragma unroll
        for (int e = 0; e < 8; e++) {
            float sv = e < 4 ? t0[e] : t1[e & 3];
            float ee = s1i + sv;
            ee = fmaxf(ee, ALPHA * ee);
            float p = __expf(ee + c1i);
            p = ((bits >> e) & 1) ? p : 0.f;
            pb[e] = f2bf(p);
        }
#pragma unroll
        for (int fm = 0; fm < 8; fm++) {
            short8 af = *(const short8*)(hb + (size_t)(fm * 16 + lr) * 1024 + jb);
            acc[fm] = __builtin_amdgcn_mfma_f32_16x16x32_bf16(af, pb, acc[fm], 0, 0, 0);
        }
    }
#pragma unroll
    for (int fm = 0; fm < 8; fm++)
#pragma unroll
        for (int r = 0; r < 4; r++)
            sacc[wave][lr][fm * 16 + lg * 4 + r] = acc[fm][r];
    __syncthreads();
    for (int e = tid; e < 2048; e += 256) {
        int li = e >> 7, o = e & 127;
        float v = sacc[0][li][o] + sacc[1][li][o] + sacc[2][li][o] + sacc[3][li][o];
        v = v > 0.f ? v : expm1f(v);
        ghat[((size_t)b * 48 + tile * 16 + li) * 128 + o] = v;
    }
}

// ---------------- Q/K/V projections, latency-parallel (32 blocks) --------------
// block (x,b): output slice o0 = x*32; K/V for 32 ctx rows, Q for row 0 of ghat.
__global__ __launch_bounds__(256) void k_qkv(
        const float* __restrict__ ghat,
        const float* __restrict__ wq, const float* __restrict__ bq,
        const float* __restrict__ wk, const float* __restrict__ bk,
        const float* __restrict__ wv, const float* __restrict__ bv,
        float* __restrict__ Qp, float* __restrict__ Kp, float* __restrict__ Vp) {
    int b = blockIdx.y, o0 = blockIdx.x * 32, t = threadIdx.x;
    __shared__ float sq[128], sctx[32][128];
    if (t < 128) sq[t] = ghat[(size_t)b * 48 * 128 + t];
    for (int e = t; e < 4096; e += 256) {
        int r = e >> 7, c = e & 127;
        sctx[r][c] = ghat[((size_t)b * 48 + 1 + r) * 128 + c];
    }
    __syncthreads();
    int j = t & 31, rbase = t >> 5, o = o0 + j;
#pragma unroll
    for (int p = 0; p < 4; p++) {
        int r = rbase + p * 8;
        float ak = bk[o], av = bv[o];
        const float* xr = sctx[r];
#pragma unroll 8
        for (int c = 0; c < 128; c++) {
            float x = xr[c];
            ak += x * wk[c * 128 + o];
            av += x * wv[c * 128 + o];
        }
        Kp[((size_t)b * 32 + r) * 128 + o] = ak;
        Vp[((size_t)b * 32 + r) * 128 + o] = av;
    }
    if (t < 32) {
        float aq = bq[o0 + t];
#pragma unroll 8
        for (int c = 0; c < 128; c++) aq += sq[c] * wq[c * 128 + o0 + t];
        Qp[b * 128 + o0 + t] = aq;
    }
}

// ---------------- tail: attention + wo + p1 + LN + relu + p2 -------------------
__global__ __launch_bounds__(256) void k_tail(
        const float* __restrict__ Qp, const float* __restrict__ Kp,
        const float* __restrict__ Vp,
        const float* __restrict__ wo, const float* __restrict__ bo,
        const float* __restrict__ p1w, const float* __restrict__ p1b,
        const float* __restrict__ lng, const float* __restrict__ lnb,
        const float* __restrict__ p2w, const float* __restrict__ p2b,
        float* __restrict__ out) {
    int b = blockIdx.x, t = threadIdx.x;
    __shared__ float sQ[128], sK[32][128], sV[32][128];
    __shared__ float sP[4][33], sO[128], sT[128], sZ[128];
    __shared__ float sred[2];

    if (t < 128) sQ[t] = Qp[b * 128 + t];
    for (int e = t; e < 4096; e += 256) {
        int r = e >> 7, c = e & 127;
        sK[r][c] = Kp[((size_t)b * 32 + r) * 128 + c];
        sV[r][c] = Vp[((size_t)b * 32 + r) * 128 + c];
    }
    __syncthreads();
    // scores + softmax, 32-lane-group parallel
    if (t < 128) {
        int hh = t >> 5, jj = t & 31;
        float s = 0.f;
#pragma unroll
        for (int d = 0; d < 32; d++) s += sQ[hh * 32 + d] * sK[jj][hh * 32 + d];
        s *= 0.17677669529663687f;   // 1/sqrt(32)
        float m = s;
#pragma unroll
        for (int off = 16; off > 0; off >>= 1) m = fmaxf(m, __shfl_xor(m, off, 32));
        float p = __expf(s - m);
        float sum = p;
#pragma unroll
        for (int off = 16; off > 0; off >>= 1) sum += __shfl_xor(sum, off, 32);
        sP[hh][jj] = p / sum;
    }
    __syncthreads();
    if (t < 128) {
        int hh = t >> 5;
        float s = 0.f;
#pragma unroll
        for (int jj = 0; jj < 32; jj++) s += sP[hh][jj] * sV[jj][t];
        sO[t] = s;
    }
    __syncthreads();
    if (t < 128) {
        float s = bo[t];
#pragma unroll 8
        for (int o = 0; o < 128; o++) s += sO[o] * wo[o * 128 + t];
        sT[t] = s;                              // pooled
    }
    __syncthreads();
    if (t < 128) {
        float s = p1b[t];
#pragma unroll 8
        for (int c = 0; c < 128; c++) s += sT[c] * p1w[c * 128 + t];
        sZ[t] = s;                              // pre-LN
    }
    __syncthreads();
    if (t < 64) {
        float v = sZ[t] + sZ[t + 64];
#pragma unroll
        for (int off = 32; off > 0; off >>= 1) v += __shfl_xor(v, off);
        if (t == 0) sred[0] = v * (1.f / 128.f);
    }
    __syncthreads();
    float mu = sred[0];
    if (t < 64) {
        float d1 = sZ[t] - mu, d2 = sZ[t + 64] - mu;
        float v = d1 * d1 + d2 * d2;
#pragma unroll
        for (int off = 32; off > 0; off >>= 1) v += __shfl_xor(v, off);
        if (t == 0) sred[1] = v * (1.f / 128.f);
    }
    __syncthreads();
    float rstd = rsqrtf(sred[1] + 1e-5f);
    if (t < 128) {
        float z = (sZ[t] - mu) * rstd * lng[t] + lnb[t];
        sT[t] = fmaxf(z, 0.f);
    }
    __syncthreads();
    for (int jj = t; jj < 768; jj += 256) {
        float s = p2b[jj];
#pragma unroll 8
        for (int o = 0; o < 128; o++) s += sT[o] * p2w[o * 768 + jj];
        out[b * 768 + jj] = s;
    }
}

extern "C" void kernel_launch(void* const* d_in, const int* in_sizes, int n_in,
                              void* d_out, int out_size, void* d_ws, size_t ws_size,
                              hipStream_t stream) {
    const float* x   = (const float*)d_in[0];
    const int*  adj  = (const int*)d_in[1];
    const int*  cidx = (const int*)d_in[2];
    const float* W1  = (const float*)d_in[3];
    const float* a11 = (const float*)d_in[4];
    const float* a21 = (const float*)d_in[5];
    const float* W2  = (const float*)d_in[6];
    const float* a12 = (const float*)d_in[7];
    const float* a22 = (const float*)d_in[8];
    const float* wq = (const float*)d_in[9];  const float* bq = (const float*)d_in[10];
    const float* wk = (const float*)d_in[11]; const float* bk = (const float*)d_in[12];
    const float* wv = (const float*)d_in[13]; const float* bv = (const float*)d_in[14];
    const float* wo = (const float*)d_in[15]; const float* bo = (const float*)d_in[16];
    const float* p1w = (const float*)d_in[17]; const float* p1b = (const float*)d_in[18];
    const float* lng = (const float*)d_in[19]; const float* lnb = (const float*)d_in[20];
    const float* p2w = (const float*)d_in[21]; const float* p2b = (const float*)d_in[22];
    float* out = (float*)d_out;

    char* ws = (char*)d_ws;
    size_t off = 0;
    auto alloc = [&](size_t bytes) -> char* {
        char* p = ws + off;
        off = (off + bytes + 255) & ~(size_t)255;
        return p;
    };
    short* Xb   = (short*)alloc(8192ull * 768 * 2);
    short* W1T  = (short*)alloc(1024ull * 768 * 2);
    short* W2T  = (short*)alloc(128ull * 1024 * 2);
    unsigned* adjb = (unsigned*)alloc(8ull * 1024 * 32 * 4);
    short* h1t  = (short*)alloc(64ull * 128 * 1024 * 2);
    float* s1a  = (float*)alloc(64ull * 1024 * 4);
    float* s2a  = (float*)alloc(64ull * 1024 * 4);
    float* c1a  = (float*)alloc(64ull * 1024 * 4);
    short* hcat = (short*)alloc(8192ull * 1024 * 2);
    short* h2t  = (short*)alloc(8ull * 128 * 1024 * 2);
    float* s1b  = (float*)alloc(8192ull * 4);
    float* s2b  = (float*)alloc(8192ull * 4);
    float* ghat = (float*)alloc(8ull * 48 * 128 * 4);
    float* Qp   = (float*)alloc(8ull * 128 * 4);
    float* Kp   = (float*)alloc(8ull * 32 * 128 * 4);
    float* Vp   = (float*)alloc(8ull * 32 * 128 * 4);
    if (off > ws_size) return;

    k_cast_x<<<6144, 256, 0, stream>>>(x, Xb, 1572864);
    k_w1t<<<3072, 256, 0, stream>>>(W1, W1T);
    k_w2t<<<512, 256, 0, stream>>>(W2, W2T);
    k_adjbits<<<32768, 256, 0, stream>>>(adj, adjb);

    // layer 1
    k_gemm_bt<<<dim3(64, 8), 256, 0, stream>>>(Xb, W1T, h1t, 768, 1024);
    k_s12<<<256, 256, 0, stream>>>(h1t, a11, a21, s1a, s2a, 8);
    k_stats<<<2048, 256, 0, stream>>>(adjb, s1a, s2a, c1a, 8);
    k_attn1<<<dim3(16, 64), 256, 0, stream>>>(h1t, adjb, s1a, s2a, c1a, hcat);

    // layer 2 (GEMM full; attention only for gathered rows)
    k_gemm_bt<<<dim3(64, 1), 256, 0, stream>>>(hcat, W2T, h2t, 1024, 128);
    k_s12<<<32, 256, 0, stream>>>(h2t, a12, a22, s1b, s2b, 1);
    k_attn2g<<<dim3(3, 8), 256, 0, stream>>>(h2t, adjb, s1b, s2b, cidx, ghat);

    // tail
    k_qkv<<<dim3(4, 8), 256, 0, stream>>>(ghat, wq, bq, wk, bk, wv, bv, Qp, Kp, Vp);
    k_tail<<<8, 256, 0, stream>>>(Qp, Kp, Vp, wo, bo, p1w, p1b, lng, lnb,
                                  p2w, p2b, out);
}

// Round 6
// 228.892 us; speedup vs baseline: 1.1030x; 1.0363x over previous
//
#include <hip/hip_runtime.h>
#include <hip/hip_bf16.h>

#define ALPHA 0.2f
#define NEGF  -9000000000000000.0f

using short8  = __attribute__((ext_vector_type(8))) short;
using short4v = __attribute__((ext_vector_type(4))) short;
using f32x4   = __attribute__((ext_vector_type(4))) float;
using int4v   = __attribute__((ext_vector_type(4))) int;

static __device__ __forceinline__ float b2f(short s) {
    union { float f; unsigned u; } v; v.u = ((unsigned)(unsigned short)s) << 16; return v.f;
}
static __device__ __forceinline__ short f2bf(float f) {
    __hip_bfloat16 h = __float2bfloat16(f);
    return *reinterpret_cast<short*>(&h);
}
static __device__ __forceinline__ void gload_lds16(const void* g, void* l) {
    __builtin_amdgcn_global_load_lds(
        (const __attribute__((address_space(1))) unsigned*)g,
        (__attribute__((address_space(3))) unsigned*)l, 16, 0, 0);
}

// ---------------- prep: casts / weight transposes / adjacency bitmask ----------
__global__ void k_cast_x(const float* __restrict__ x, short* __restrict__ xb, int n4) {
    int idx = blockIdx.x * blockDim.x + threadIdx.x;
    if (idx < n4) {
        f32x4 v = ((const f32x4*)x)[idx];
        short4v o;
        o[0] = f2bf(v[0]); o[1] = f2bf(v[1]); o[2] = f2bf(v[2]); o[3] = f2bf(v[3]);
        ((short4v*)xb)[idx] = o;
    }
}

__global__ void k_w1t(const float* __restrict__ W1, short* __restrict__ Wt) {
    int idx = blockIdx.x * blockDim.x + threadIdx.x;
    if (idx < 1024 * 768) {
        int n = idx / 768, k = idx - n * 768;
        int h = n >> 7, o = n & 127;
        Wt[idx] = f2bf(W1[(h * 768 + k) * 128 + o]);
    }
}
__global__ void k_w2t(const float* __restrict__ W2, short* __restrict__ Wt) {
    int idx = blockIdx.x * blockDim.x + threadIdx.x;
    if (idx < 128 * 1024) {
        int n = idx >> 10, k = idx & 1023;
        Wt[idx] = f2bf(W2[k * 128 + n]);
    }
}

// adj int32 (0/1) -> bit-packed: adjb[(b*1024+i)*32 + j/32], bit j%32
__global__ void k_adjbits(const int* __restrict__ adj, unsigned* __restrict__ adjb) {
    int idx = blockIdx.x * blockDim.x + threadIdx.x;   // 8M elements
    int lane = threadIdx.x & 63;
    unsigned long long m = __ballot(adj[idx] > 0);
    if ((lane & 31) == 0) adjb[idx >> 5] = (unsigned)(m >> (lane & 32));
}

// ---------------- bf16 MFMA GEMM 128x128 (LDS dbuf, swizzled, XCD-swz) ---------
__global__ __launch_bounds__(256) void k_gemm_bt(
        const short* __restrict__ A, const short* __restrict__ Bt,
        short* __restrict__ Ct, int K, int Ncols) {
    int tid = threadIdx.x, wave = tid >> 6, lane = tid & 63;
    int lr = lane & 15, lg = lane >> 4;
    // XCD-aware bijective swizzle (nwg % 8 == 0)
    int flat = blockIdx.y * gridDim.x + blockIdx.x;
    int chunkw = (gridDim.x * gridDim.y) >> 3;
    int swz = (flat & 7) * chunkw + (flat >> 3);
    int bx = swz % gridDim.x, by = swz / gridDim.x;
    int m0 = bx * 128, n0 = by * 128;
    int wm = (wave >> 1) * 64, wn = (wave & 1) * 64;
    __shared__ short lsA[2][128 * 32], lsB[2][128 * 32];
    f32x4 acc[4][4];
#pragma unroll
    for (int i = 0; i < 4; i++)
#pragma unroll
        for (int j = 0; j < 4; j++) acc[i][j] = (f32x4){0.f, 0.f, 0.f, 0.f};

    auto stage = [&](int bufsel, int k0) {
#pragma unroll
        for (int s = 0; s < 2; s++) {
            int chunk = s * 256 + tid;          // 0..511 (16B chunks)
            int r = chunk >> 2, c = chunk & 3;
            int csrc = c ^ (r & 3);             // inverse-swizzled source
            int base = (s * 256 + wave * 64) * 8;  // shorts, wave-uniform
            gload_lds16(A + (size_t)(m0 + r) * K + k0 + csrc * 8, &lsA[bufsel][base]);
            gload_lds16(Bt + (size_t)(n0 + r) * K + k0 + csrc * 8, &lsB[bufsel][base]);
        }
    };
    stage(0, 0);
    __syncthreads();
    int buf = 0;
    for (int k0 = 0; k0 < K; k0 += 32) {
        if (k0 + 32 < K) stage(buf ^ 1, k0 + 32);
        short8 a[4], bb[4];
#pragma unroll
        for (int f = 0; f < 4; f++) {
            int ra = wm + f * 16 + lr, rb = wn + f * 16 + lr;
            a[f]  = *(const short8*)(&lsA[buf][ra * 32 + ((lg ^ (ra & 3)) * 8)]);
            bb[f] = *(const short8*)(&lsB[buf][rb * 32 + ((lg ^ (rb & 3)) * 8)]);
        }
#pragma unroll
        for (int fm = 0; fm < 4; fm++)
#pragma unroll
            for (int fn = 0; fn < 4; fn++)
                acc[fm][fn] = __builtin_amdgcn_mfma_f32_16x16x32_bf16(a[fm], bb[fn], acc[fm][fn], 0, 0, 0);
        __syncthreads();
        buf ^= 1;
    }
#pragma unroll
    for (int fm = 0; fm < 4; fm++) {
        int mb = m0 + wm + fm * 16 + lg * 4;
        size_t obase = ((size_t)(mb >> 10) * Ncols) * 1024 + (mb & 1023);
#pragma unroll
        for (int fn = 0; fn < 4; fn++) {
            int n = n0 + wn + fn * 16 + lr;
            short4v st;
            st[0] = f2bf(acc[fm][fn][0]); st[1] = f2bf(acc[fm][fn][1]);
            st[2] = f2bf(acc[fm][fn][2]); st[3] = f2bf(acc[fm][fn][3]);
            *(short4v*)(Ct + obase + (size_t)n * 1024) = st;
        }
    }
}

// ---------------- bf16 MFMA GEMM 64x64 (for small-N gemm2; 4x grid) ------------
__global__ __launch_bounds__(256) void k_gemm64(
        const short* __restrict__ A, const short* __restrict__ Bt,
        short* __restrict__ Ct, int K, int Ncols) {
    int tid = threadIdx.x, wave = tid >> 6, lane = tid & 63;
    int lr = lane & 15, lg = lane >> 4;
    int flat = blockIdx.y * gridDim.x + blockIdx.x;
    int chunkw = (gridDim.x * gridDim.y) >> 3;
    int swz = (flat & 7) * chunkw + (flat >> 3);
    int bx = swz % gridDim.x, by = swz / gridDim.x;
    int m0 = bx * 64, n0 = by * 64;
    int wm = (wave >> 1) * 32, wn = (wave & 1) * 32;
    __shared__ short lsA[2][64 * 32], lsB[2][64 * 32];
    f32x4 acc[2][2];
#pragma unroll
    for (int i = 0; i < 2; i++)
#pragma unroll
        for (int j = 0; j < 2; j++) acc[i][j] = (f32x4){0.f, 0.f, 0.f, 0.f};

    auto stage = [&](int bufsel, int k0) {
        int r = tid >> 2, c = tid & 3;          // 256 chunks, 1 per thread
        int csrc = c ^ (r & 3);
        int base = (wave * 64) * 8;
        gload_lds16(A + (size_t)(m0 + r) * K + k0 + csrc * 8, &lsA[bufsel][base]);
        gload_lds16(Bt + (size_t)(n0 + r) * K + k0 + csrc * 8, &lsB[bufsel][base]);
    };
    stage(0, 0);
    __syncthreads();
    int buf = 0;
    for (int k0 = 0; k0 < K; k0 += 32) {
        if (k0 + 32 < K) stage(buf ^ 1, k0 + 32);
        short8 a[2], bb[2];
#pragma unroll
        for (int f = 0; f < 2; f++) {
            int ra = wm + f * 16 + lr, rb = wn + f * 16 + lr;
            a[f]  = *(const short8*)(&lsA[buf][ra * 32 + ((lg ^ (ra & 3)) * 8)]);
            bb[f] = *(const short8*)(&lsB[buf][rb * 32 + ((lg ^ (rb & 3)) * 8)]);
        }
#pragma unroll
        for (int fm = 0; fm < 2; fm++)
#pragma unroll
            for (int fn = 0; fn < 2; fn++)
                acc[fm][fn] = __builtin_amdgcn_mfma_f32_16x16x32_bf16(a[fm], bb[fn], acc[fm][fn], 0, 0, 0);
        __syncthreads();
        buf ^= 1;
    }
#pragma unroll
    for (int fm = 0; fm < 2; fm++) {
        int mb = m0 + wm + fm * 16 + lg * 4;
        size_t obase = ((size_t)(mb >> 10) * Ncols) * 1024 + (mb & 1023);
#pragma unroll
        for (int fn = 0; fn < 2; fn++) {
            int n = n0 + wn + fn * 16 + lr;
            short4v st;
            st[0] = f2bf(acc[fm][fn][0]); st[1] = f2bf(acc[fm][fn][1]);
            st[2] = f2bf(acc[fm][fn][2]); st[3] = f2bf(acc[fm][fn][3]);
            *(short4v*)(Ct + obase + (size_t)n * 1024) = st;
        }
    }
}

// ---------------- s1/s2 = h . a1 / h . a2 (reads transposed h: [bh][o][i]) ------
__global__ __launch_bounds__(256) void k_s12(
        const short* __restrict__ ht, const float* __restrict__ a1,
        const float* __restrict__ a2, float* __restrict__ s1,
        float* __restrict__ s2, int nh) {
    int bh = blockIdx.x >> 2;
    int i = ((blockIdx.x & 3) << 8) + threadIdx.x;
    int h = bh % nh;
    const short* base = ht + (size_t)bh * 131072 + i;
    float acc1 = 0.f, acc2 = 0.f;
#pragma unroll 8
    for (int o = 0; o < 128; o++) {
        float v = b2f(base[(size_t)o << 10]);
        acc1 += v * a1[h * 128 + o];
        acc2 += v * a2[h * 128 + o];
    }
    s1[bh * 1024 + i] = acc1;
    s2[bh * 1024 + i] = acc2;
}

// ---------------- per-row softmax stats: c1 = -max - log(sum) ----------------
__global__ __launch_bounds__(256) void k_stats(
        const unsigned* __restrict__ adjb, const float* __restrict__ s1,
        const float* __restrict__ s2, float* __restrict__ c1a, int nh) {
    int w = blockIdx.x * 4 + (threadIdx.x >> 6);
    int lane = threadIdx.x & 63;
    int b = w >> 10, i = w & 1023;
    const unsigned long long* ab =
        (const unsigned long long*)(adjb + ((size_t)(b << 10) + i) * 32);
    unsigned long long aw[16];
#pragma unroll
    for (int jc = 0; jc < 16; jc++) aw[jc] = ab[jc];
    for (int h = 0; h < nh; h++) {
        int bh = b * nh + h;
        float s1i = s1[bh * 1024 + i];
        const float* s2r = s2 + bh * 1024;
        float e[16];
        float m = -3.4e38f;
#pragma unroll
        for (int jc = 0; jc < 16; jc++) {
            float ee = s1i + s2r[jc * 64 + lane];
            ee = fmaxf(ee, ALPHA * ee);
            ee = ((aw[jc] >> lane) & 1) ? ee : NEGF;
            e[jc] = ee;
            m = fmaxf(m, ee);
        }
#pragma unroll
        for (int off = 32; off > 0; off >>= 1) m = fmaxf(m, __shfl_xor(m, off));
        float s = 0.f;
#pragma unroll
        for (int jc = 0; jc < 16; jc++) s += __expf(e[jc] - m);
#pragma unroll
        for (int off = 32; off > 0; off >>= 1) s += __shfl_xor(s, off);
        if (lane == 0) c1a[bh * 1024 + i] = -m - __logf(s);
    }
}

// ---------------- GAT layer-1 attention: 8 waves, 128 i-rows per block ---------
__global__ __launch_bounds__(512) void k_attn1(
        const short* __restrict__ ht, const unsigned* __restrict__ adjb,
        const float* __restrict__ s1, const float* __restrict__ s2,
        const float* __restrict__ c1a, short* __restrict__ out) {
    int bh = blockIdx.y;
    int b = bh >> 3, h = bh & 7;
    int tid = threadIdx.x, wave = tid >> 6, lane = tid & 63;
    int lr = lane & 15, lg = lane >> 4;
    int ic = blockIdx.x * 128 + wave * 16 + lr;
    int row = bh * 1024 + ic;
    float s1i = s1[row], c1i = c1a[row];
    const unsigned long long* abrow =
        (const unsigned long long*)(adjb + ((size_t)(b << 10) + ic) * 32);
    const float* s2r = s2 + bh * 1024;
    const short* hbase = ht + (size_t)bh * 131072;

    __shared__ short lsh[2][8192];   // [128 o][64 j] bf16, chunk-XOR swizzled
    f32x4 acc[8];
#pragma unroll
    for (int f = 0; f < 8; f++) acc[f] = (f32x4){0.f, 0.f, 0.f, 0.f};

    auto stage = [&](int bufsel, int j0) {
#pragma unroll
        for (int s = 0; s < 2; s++) {
            int chunk = s * 512 + tid;       // 0..1023 (16B chunks)
            int r = chunk >> 3, c = chunk & 7;
            int csrc = c ^ (r & 7);          // inverse-swizzle the SOURCE
            gload_lds16(hbase + (size_t)r * 1024 + j0 + csrc * 8,
                        &lsh[bufsel][(s * 512 + wave * 64) * 8]);
        }
    };
    stage(0, 0);
    __syncthreads();
    int buf = 0;
    for (int j0 = 0; j0 < 1024; j0 += 64) {
        if (j0 < 960) stage(buf ^ 1, j0 + 64);
        unsigned long long aw = abrow[j0 >> 6];
#pragma unroll
        for (int kk = 0; kk < 2; kk++) {
            int jb = j0 + kk * 32 + lg * 8;
            f32x4 t0 = *(const f32x4*)(s2r + jb);
            f32x4 t1 = *(const f32x4*)(s2r + jb + 4);
            unsigned bits = (unsigned)(aw >> (kk * 32 + lg * 8)) & 0xFFu;
            float pv[8];
#pragma unroll
            for (int e = 0; e < 8; e++) {
                float sv = e < 4 ? t0[e] : t1[e & 3];
                float ee = s1i + sv;
                ee = fmaxf(ee, ALPHA * ee);
                float p = __expf(ee + c1i);
                pv[e] = ((bits >> e) & 1) ? p : 0.f;
            }
            int4v pw;
#pragma unroll
            for (int w = 0; w < 4; w++) {
                int d;
                asm("v_cvt_pk_bf16_f32 %0, %1, %2"
                    : "=v"(d) : "v"(pv[2 * w]), "v"(pv[2 * w + 1]));
                pw[w] = d;
            }
            short8 pb = __builtin_bit_cast(short8, pw);
#pragma unroll
            for (int fm = 0; fm < 8; fm++) {
                int r = fm * 16 + lr;
                int ck = (kk * 4 + lg) ^ (r & 7);   // swizzled read
                short8 af = *(const short8*)(&lsh[buf][r * 64 + ck * 8]);
                acc[fm] = __builtin_amdgcn_mfma_f32_16x16x32_bf16(af, pb, acc[fm], 0, 0, 0);
            }
        }
        __syncthreads();
        buf ^= 1;
    }
    size_t orow = ((size_t)(b << 10) + ic) * 1024 + h * 128;
#pragma unroll
    for (int fm = 0; fm < 8; fm++) {
        int ob = (fm << 4) + lg * 4;
        short4v st;
#pragma unroll
        for (int r = 0; r < 4; r++) {
            float x = acc[fm][r];
            x = x > 0.f ? x : expm1f(x);
            st[r] = f2bf(x);
        }
        *(short4v*)(out + orow + ob) = st;
    }
}

// ---------------- layer-2 attention, GATHERED rows only (33 per batch) ---------
__global__ __launch_bounds__(256) void k_attn2g(
        const short* __restrict__ h2t, const unsigned* __restrict__ adjb,
        const float* __restrict__ s1, const float* __restrict__ s2,
        const int* __restrict__ cidx, float* __restrict__ ghat) {
    int tile = blockIdx.x;      // 0..2
    int b = blockIdx.y;         // 0..7
    int tid = threadIdx.x, wave = tid >> 6, lane = tid & 63;
    int lr = lane & 15, lg = lane >> 4;

    __shared__ int nodes[16];
    __shared__ float sc1[16];
    __shared__ float sacc[4][16][129];

    if (tid < 16) {
        int pos = tile * 16 + tid;
        int nd = 0;
        if (pos >= 1 && pos <= 32) nd = cidx[b * 32 + pos - 1];
        nodes[tid] = nd;
    }
    __syncthreads();

    const float* s2r = s2 + b * 1024;
    for (int q = 0; q < 4; q++) {
        int li = wave * 4 + q;
        int nd = nodes[li];
        float s1i = s1[b * 1024 + nd];
        const unsigned long long* ab =
            (const unsigned long long*)(adjb + ((size_t)(b << 10) + nd) * 32);
        float ev[16];
        float m = -3.4e38f;
#pragma unroll
        for (int c = 0; c < 16; c++) {
            float ee = s1i + s2r[c * 64 + lane];
            ee = fmaxf(ee, ALPHA * ee);
            ee = ((ab[c] >> lane) & 1) ? ee : NEGF;
            ev[c] = ee;
            m = fmaxf(m, ee);
        }
#pragma unroll
        for (int off = 32; off > 0; off >>= 1) m = fmaxf(m, __shfl_xor(m, off));
        float s = 0.f;
#pragma unroll
        for (int c = 0; c < 16; c++) s += __expf(ev[c] - m);
#pragma unroll
        for (int off = 32; off > 0; off >>= 1) s += __shfl_xor(s, off);
        if (lane == 0) sc1[li] = -m - __logf(s);
    }
    __syncthreads();

    int nd = nodes[lr];
    float s1i = s1[b * 1024 + nd];
    float c1i = sc1[lr];
    const unsigned long long* abrow =
        (const unsigned long long*)(adjb + ((size_t)(b << 10) + nd) * 32);
    const short* hb = h2t + (size_t)b * 131072;
    f32x4 acc[8];
#pragma unroll
    for (int f = 0; f < 8; f++) acc[f] = (f32x4){0.f, 0.f, 0.f, 0.f};

    for (int j0 = wave * 256; j0 < wave * 256 + 256; j0 += 32) {
        int jb = j0 + lg * 8;
        f32x4 t0 = *(const f32x4*)(s2r + jb);
        f32x4 t1 = *(const f32x4*)(s2r + jb + 4);
        unsigned bits = (unsigned)(abrow[j0 >> 6] >> ((j0 & 32) + lg * 8)) & 0xFFu;
        short8 pb;
#pragma unroll
        for (int e = 0; e < 8; e++) {
            float sv = e < 4 ? t0[e] : t1[e & 3];
            float ee = s1i + sv;
            ee = fmaxf(ee, ALPHA * ee);
            float p = __expf(ee + c1i);
            p = ((bits >> e) & 1) ? p : 0.f;
            pb[e] = f2bf(p);
        }
#pragma unroll
        for (int fm = 0; fm < 8; fm++) {
            short8 af = *(const short8*)(hb + (size_t)(fm * 16 + lr) * 1024 + jb);
            acc[fm] = __builtin_amdgcn_mfma_f32_16x16x32_bf16(af, pb, acc[fm], 0, 0, 0);
        }
    }
#pragma unroll
    for (int fm = 0; fm < 8; fm++)
#pragma unroll
        for (int r = 0; r < 4; r++)
            sacc[wave][lr][fm * 16 + lg * 4 + r] = acc[fm][r];
    __syncthreads();
    for (int e = tid; e < 2048; e += 256) {
        int li = e >> 7, o = e & 127;
        float v = sacc[0][li][o] + sacc[1][li][o] + sacc[2][li][o] + sacc[3][li][o];
        v = v > 0.f ? v : expm1f(v);
        ghat[((size_t)b * 48 + tile * 16 + li) * 128 + o] = v;
    }
}

// ---------------- K/V projections with LDS-staged weight slices ----------------
// grid (16, 8): bx&7 = row-group (4 ctx rows), bx>>3 = o-half (64 cols)
__global__ __launch_bounds__(256) void k_qkv(
        const float* __restrict__ ghat,
        const float* __restrict__ wk, const float* __restrict__ bk,
        const float* __restrict__ wv, const float* __restrict__ bv,
        float* __restrict__ Kp, float* __restrict__ Vp) {
    int b = blockIdx.y, rg = blockIdx.x & 7, o0 = (blockIdx.x >> 3) * 64;
    int t = threadIdx.x, wave = t >> 6, lane = t & 63;
    __shared__ float sx[4][128];
    __shared__ float sWk[128 * 64], sWv[128 * 64];

    for (int e = t; e < 512; e += 256) {
        int r = e >> 7, c = e & 127;
        sx[r][c] = ghat[((size_t)b * 48 + 1 + rg * 4 + r) * 128 + c];
    }
    for (int f = t; f < 2048; f += 256) {      // 2048 f32x4 per matrix slice
        int rw = f >> 4, c4 = f & 15;
        ((f32x4*)sWk)[f] = *(const f32x4*)(wk + rw * 128 + o0 + c4 * 4);
        ((f32x4*)sWv)[f] = *(const f32x4*)(wv + rw * 128 + o0 + c4 * 4);
    }
    __syncthreads();
    int o = o0 + lane;                          // wave = ctx row (0..3)
    float ka = bk[o], va = bv[o];
#pragma unroll 32
    for (int c = 0; c < 128; c++) {
        float x = sx[wave][c];
        ka += x * sWk[c * 64 + lane];
        va += x * sWv[c * 64 + lane];
    }
    int r = rg * 4 + wave;
    Kp[((size_t)b * 32 + r) * 128 + o] = ka;
    Vp[((size_t)b * 32 + r) * 128 + o] = va;
}

// ---------------- tail: Qproj + MHA + wo + p1 + LN + relu + p2 -----------------
__global__ __launch_bounds__(256) void k_tail(
        const float* __restrict__ ghat, const float* __restrict__ Kp,
        const float* __restrict__ Vp,
        const float* __restrict__ wq, const float* __restrict__ bq,
        const float* __restrict__ wo, const float* __restrict__ bo,
        const float* __restrict__ p1w, const float* __restrict__ p1b,
        const float* __restrict__ lng, const float* __restrict__ lnb,
        const float* __restrict__ p2w, const float* __restrict__ p2b,
        float* __restrict__ out) {
    int b = blockIdx.x, t = threadIdx.x;
    __shared__ float sq[128], sQ[128], sK[32][128], sV[32][128];
    __shared__ float sP[4][33], sO[128], sT[128], sZ[128];
    __shared__ float sred[2];
    __shared__ float sW[128 * 128];   // 64KB staged-weight buffer (reused)

    // phase 1: load activations + stage wq
    if (t < 128) sq[t] = ghat[(size_t)b * 48 * 128 + t];
    for (int e = t; e < 4096; e += 256) {
        int r = e >> 7, c = e & 127;
        sK[r][c] = Kp[((size_t)b * 32 + r) * 128 + c];
        sV[r][c] = Vp[((size_t)b * 32 + r) * 128 + c];
    }
    for (int f = t; f < 4096; f += 256) ((f32x4*)sW)[f] = ((const f32x4*)wq)[f];
    __syncthreads();
    // phase 2: Q projection
    if (t < 128) {
        float a0 = 0.f, a1 = 0.f, a2 = 0.f, a3 = 0.f;
#pragma unroll
        for (int c = 0; c < 128; c += 4) {
            a0 += sq[c]     * sW[c * 128 + t];
            a1 += sq[c + 1] * sW[(c + 1) * 128 + t];
            a2 += sq[c + 2] * sW[(c + 2) * 128 + t];
            a3 += sq[c + 3] * sW[(c + 3) * 128 + t];
        }
        sQ[t] = bq[t] + ((a0 + a1) + (a2 + a3));
    }
    __syncthreads();
    // phase 3: stage wo + scores/softmax
    for (int f = t; f < 4096; f += 256) ((f32x4*)sW)[f] = ((const f32x4*)wo)[f];
    if (t < 128) {
        int hh = t >> 5, jj = t & 31;
        float s = 0.f;
#pragma unroll
        for (int d = 0; d < 32; d++) s += sQ[hh * 32 + d] * sK[jj][hh * 32 + d];
        s *= 0.17677669529663687f;   // 1/sqrt(32)
        float m = s;
#pragma unroll
        for (int off = 16; off > 0; off >>= 1) m = fmaxf(m, __shfl_xor(m, off, 32));
        float p = __expf(s - m);
        float sum = p;
#pragma unroll
        for (int off = 16; off > 0; off >>= 1) sum += __shfl_xor(sum, off, 32);
        sP[hh][jj] = p / sum;
    }
    __syncthreads();
    // phase 4: PV
    if (t < 128) {
        int hh = t >> 5;
        float s = 0.f;
#pragma unroll
        for (int jj = 0; jj < 32; jj++) s += sP[hh][jj] * sV[jj][t];
        sO[t] = s;
    }
    __syncthreads();
    // phase 5: wo GEMV
    if (t < 128) {
        float a0 = 0.f, a1 = 0.f, a2 = 0.f, a3 = 0.f;
#pragma unroll
        for (int c = 0; c < 128; c += 4) {
            a0 += sO[c]     * sW[c * 128 + t];
            a1 += sO[c + 1] * sW[(c + 1) * 128 + t];
            a2 += sO[c + 2] * sW[(c + 2) * 128 + t];
            a3 += sO[c + 3] * sW[(c + 3) * 128 + t];
        }
        sT[t] = bo[t] + ((a0 + a1) + (a2 + a3));
    }
    __syncthreads();
    // phase 6: stage p1w
    for (int f = t; f < 4096; f += 256) ((f32x4*)sW)[f] = ((const f32x4*)p1w)[f];
    __syncthreads();
    // phase 7: p1 GEMV
    if (t < 128) {
        float a0 = 0.f, a1 = 0.f, a2 = 0.f, a3 = 0.f;
#pragma unroll
        for (int c = 0; c < 128; c += 4) {
            a0 += sT[c]     * sW[c * 128 + t];
            a1 += sT[c + 1] * sW[(c + 1) * 128 + t];
            a2 += sT[c + 2] * sW[(c + 2) * 128 + t];
            a3 += sT[c + 3] * sW[(c + 3) * 128 + t];
        }
        sZ[t] = p1b[t] + ((a0 + a1) + (a2 + a3));
    }
    __syncthreads();
    // phase 8: LayerNorm + ReLU
    if (t < 64) {
        float v = sZ[t] + sZ[t + 64];
#pragma unroll
        for (int off = 32; off > 0; off >>= 1) v += __shfl_xor(v, off);
        if (t == 0) sred[0] = v * (1.f / 128.f);
    }
    __syncthreads();
    float mu = sred[0];
    if (t < 64) {
        float d1 = sZ[t] - mu, d2 = sZ[t + 64] - mu;
        float v = d1 * d1 + d2 * d2;
#pragma unroll
        for (int off = 32; off > 0; off >>= 1) v += __shfl_xor(v, off);
        if (t == 0) sred[1] = v * (1.f / 128.f);
    }
    __syncthreads();
    float rstd = rsqrtf(sred[1] + 1e-5f);
    if (t < 128) {
        float z = (sZ[t] - mu) * rstd * lng[t] + lnb[t];
        sT[t] = fmaxf(z, 0.f);
    }
    __syncthreads();
    // phase 9: p2 (direct global, deep pipelined)
    for (int jj = t; jj < 768; jj += 256) {
        float a0 = 0.f, a1 = 0.f, a2 = 0.f, a3 = 0.f;
#pragma unroll
        for (int c = 0; c < 128; c += 4) {
            a0 += sT[c]     * p2w[c * 768 + jj];
            a1 += sT[c + 1] * p2w[(c + 1) * 768 + jj];
            a2 += sT[c + 2] * p2w[(c + 2) * 768 + jj];
            a3 += sT[c + 3] * p2w[(c + 3) * 768 + jj];
        }
        out[b * 768 + jj] = p2b[jj] + ((a0 + a1) + (a2 + a3));
    }
}

extern "C" void kernel_launch(void* const* d_in, const int* in_sizes, int n_in,
                              void* d_out, int out_size, void* d_ws, size_t ws_size,
                              hipStream_t stream) {
    const float* x   = (const float*)d_in[0];
    const int*  adj  = (const int*)d_in[1];
    const int*  cidx = (const int*)d_in[2];
    const float* W1  = (const float*)d_in[3];
    const float* a11 = (const float*)d_in[4];
    const float* a21 = (const float*)d_in[5];
    const float* W2  = (const float*)d_in[6];
    const float* a12 = (const float*)d_in[7];
    const float* a22 = (const float*)d_in[8];
    const float* wq = (const float*)d_in[9];  const float* bq = (const float*)d_in[10];
    const float* wk = (const float*)d_in[11]; const float* bk = (const float*)d_in[12];
    const float* wv = (const float*)d_in[13]; const float* bv = (const float*)d_in[14];
    const float* wo = (const float*)d_in[15]; const float* bo = (const float*)d_in[16];
    const float* p1w = (const float*)d_in[17]; const float* p1b = (const float*)d_in[18];
    const float* lng = (const float*)d_in[19]; const float* lnb = (const float*)d_in[20];
    const float* p2w = (const float*)d_in[21]; const float* p2b = (const float*)d_in[22];
    float* out = (float*)d_out;

    char* ws = (char*)d_ws;
    size_t off = 0;
    auto alloc = [&](size_t bytes) -> char* {
        char* p = ws + off;
        off = (off + bytes + 255) & ~(size_t)255;
        return p;
    };
    short* Xb   = (short*)alloc(8192ull * 768 * 2);
    short* W1T  = (short*)alloc(1024ull * 768 * 2);
    short* W2T  = (short*)alloc(128ull * 1024 * 2);
    unsigned* adjb = (unsigned*)alloc(8ull * 1024 * 32 * 4);
    short* h1t  = (short*)alloc(64ull * 128 * 1024 * 2);
    float* s1a  = (float*)alloc(64ull * 1024 * 4);
    float* s2a  = (float*)alloc(64ull * 1024 * 4);
    float* c1a  = (float*)alloc(64ull * 1024 * 4);
    short* hcat = (short*)alloc(8192ull * 1024 * 2);
    short* h2t  = (short*)alloc(8ull * 128 * 1024 * 2);
    float* s1b  = (float*)alloc(8192ull * 4);
    float* s2b  = (float*)alloc(8192ull * 4);
    float* ghat = (float*)alloc(8ull * 48 * 128 * 4);
    float* Kp   = (float*)alloc(8ull * 32 * 128 * 4);
    float* Vp   = (float*)alloc(8ull * 32 * 128 * 4);
    if (off > ws_size) return;

    k_cast_x<<<6144, 256, 0, stream>>>(x, Xb, 1572864);
    k_w1t<<<3072, 256, 0, stream>>>(W1, W1T);
    k_w2t<<<512, 256, 0, stream>>>(W2, W2T);
    k_adjbits<<<32768, 256, 0, stream>>>(adj, adjb);

    // layer 1
    k_gemm_bt<<<dim3(64, 8), 256, 0, stream>>>(Xb, W1T, h1t, 768, 1024);
    k_s12<<<256, 256, 0, stream>>>(h1t, a11, a21, s1a, s2a, 8);
    k_stats<<<2048, 256, 0, stream>>>(adjb, s1a, s2a, c1a, 8);
    k_attn1<<<dim3(8, 64), 512, 0, stream>>>(h1t, adjb, s1a, s2a, c1a, hcat);

    // layer 2 (GEMM full; attention only for gathered rows)
    k_gemm64<<<dim3(128, 2), 256, 0, stream>>>(hcat, W2T, h2t, 1024, 128);
    k_s12<<<32, 256, 0, stream>>>(h2t, a12, a22, s1b, s2b, 1);
    k_attn2g<<<dim3(3, 8), 256, 0, stream>>>(h2t, adjb, s1b, s2b, cidx, ghat);

    // tail
    k_qkv<<<dim3(16, 8), 256, 0, stream>>>(ghat, wk, bk, wv, bv, Kp, Vp);
    k_tail<<<8, 256, 0, stream>>>(ghat, Kp, Vp, wq, bq, wo, bo,
                                  p1w, p1b, lng, lnb, p2w, p2b, out);
}

// Round 7
// 192.966 us; speedup vs baseline: 1.3083x; 1.1862x over previous
//
#include <hip/hip_runtime.h>
#include <hip/hip_bf16.h>

#define ALPHA 0.2f
#define NEGF  -9000000000000000.0f

using short8  = __attribute__((ext_vector_type(8))) short;
using short4v = __attribute__((ext_vector_type(4))) short;
using f32x4   = __attribute__((ext_vector_type(4))) float;
using int4v   = __attribute__((ext_vector_type(4))) int;

static __device__ __forceinline__ float b2f(short s) {
    union { float f; unsigned u; } v; v.u = ((unsigned)(unsigned short)s) << 16; return v.f;
}
static __device__ __forceinline__ short f2bf(float f) {
    __hip_bfloat16 h = __float2bfloat16(f);
    return *reinterpret_cast<short*>(&h);
}
static __device__ __forceinline__ void gload_lds16(const void* g, void* l) {
    __builtin_amdgcn_global_load_lds(
        (const __attribute__((address_space(1))) unsigned*)g,
        (__attribute__((address_space(3))) unsigned*)l, 16, 0, 0);
}

// ---------------- prep: casts / weight transposes / adjacency bitmask ----------
__global__ void k_cast_x(const float* __restrict__ x, short* __restrict__ xb, int n4) {
    int idx = blockIdx.x * blockDim.x + threadIdx.x;
    if (idx < n4) {
        f32x4 v = ((const f32x4*)x)[idx];
        short4v o;
        o[0] = f2bf(v[0]); o[1] = f2bf(v[1]); o[2] = f2bf(v[2]); o[3] = f2bf(v[3]);
        ((short4v*)xb)[idx] = o;
    }
}

__global__ void k_w1t(const float* __restrict__ W1, short* __restrict__ Wt) {
    int idx = blockIdx.x * blockDim.x + threadIdx.x;
    if (idx < 1024 * 768) {
        int n = idx / 768, k = idx - n * 768;
        int h = n >> 7, o = n & 127;
        Wt[idx] = f2bf(W1[(h * 768 + k) * 128 + o]);
    }
}
__global__ void k_w2t(const float* __restrict__ W2, short* __restrict__ Wt) {
    int idx = blockIdx.x * blockDim.x + threadIdx.x;
    if (idx < 128 * 1024) {
        int n = idx >> 10, k = idx & 1023;
        Wt[idx] = f2bf(W2[k * 128 + n]);
    }
}

// adj int32 (0/1) -> bit-packed: adjb[(b*1024+i)*32 + j/32], bit j%32
__global__ void k_adjbits(const int* __restrict__ adj, unsigned* __restrict__ adjb) {
    int idx = blockIdx.x * blockDim.x + threadIdx.x;   // 8M elements
    int lane = threadIdx.x & 63;
    unsigned long long m = __ballot(adj[idx] > 0);
    if ((lane & 31) == 0) adjb[idx >> 5] = (unsigned)(m >> (lane & 32));
}

// ---------------- bf16 MFMA GEMM 128x128 (LDS dbuf, swizzled, XCD-swz) ---------
__global__ __launch_bounds__(256) void k_gemm_bt(
        const short* __restrict__ A, const short* __restrict__ Bt,
        short* __restrict__ Ct, int K, int Ncols) {
    int tid = threadIdx.x, wave = tid >> 6, lane = tid & 63;
    int lr = lane & 15, lg = lane >> 4;
    // XCD-aware bijective swizzle (nwg % 8 == 0)
    int flat = blockIdx.y * gridDim.x + blockIdx.x;
    int chunkw = (gridDim.x * gridDim.y) >> 3;
    int swz = (flat & 7) * chunkw + (flat >> 3);
    int bx = swz % gridDim.x, by = swz / gridDim.x;
    int m0 = bx * 128, n0 = by * 128;
    int wm = (wave >> 1) * 64, wn = (wave & 1) * 64;
    __shared__ short lsA[2][128 * 32], lsB[2][128 * 32];
    f32x4 acc[4][4];
#pragma unroll
    for (int i = 0; i < 4; i++)
#pragma unroll
        for (int j = 0; j < 4; j++) acc[i][j] = (f32x4){0.f, 0.f, 0.f, 0.f};

    auto stage = [&](int bufsel, int k0) {
#pragma unroll
        for (int s = 0; s < 2; s++) {
            int chunk = s * 256 + tid;          // 0..511 (16B chunks)
            int r = chunk >> 2, c = chunk & 3;
            int csrc = c ^ (r & 3);             // inverse-swizzled source
            int base = (s * 256 + wave * 64) * 8;  // shorts, wave-uniform
            gload_lds16(A + (size_t)(m0 + r) * K + k0 + csrc * 8, &lsA[bufsel][base]);
            gload_lds16(Bt + (size_t)(n0 + r) * K + k0 + csrc * 8, &lsB[bufsel][base]);
        }
    };
    stage(0, 0);
    __syncthreads();
    int buf = 0;
    for (int k0 = 0; k0 < K; k0 += 32) {
        if (k0 + 32 < K) stage(buf ^ 1, k0 + 32);
        short8 a[4], bb[4];
#pragma unroll
        for (int f = 0; f < 4; f++) {
            int ra = wm + f * 16 + lr, rb = wn + f * 16 + lr;
            a[f]  = *(const short8*)(&lsA[buf][ra * 32 + ((lg ^ (ra & 3)) * 8)]);
            bb[f] = *(const short8*)(&lsB[buf][rb * 32 + ((lg ^ (rb & 3)) * 8)]);
        }
#pragma unroll
        for (int fm = 0; fm < 4; fm++)
#pragma unroll
            for (int fn = 0; fn < 4; fn++)
                acc[fm][fn] = __builtin_amdgcn_mfma_f32_16x16x32_bf16(a[fm], bb[fn], acc[fm][fn], 0, 0, 0);
        __syncthreads();
        buf ^= 1;
    }
#pragma unroll
    for (int fm = 0; fm < 4; fm++) {
        int mb = m0 + wm + fm * 16 + lg * 4;
        size_t obase = ((size_t)(mb >> 10) * Ncols) * 1024 + (mb & 1023);
#pragma unroll
        for (int fn = 0; fn < 4; fn++) {
            int n = n0 + wn + fn * 16 + lr;
            short4v st;
            st[0] = f2bf(acc[fm][fn][0]); st[1] = f2bf(acc[fm][fn][1]);
            st[2] = f2bf(acc[fm][fn][2]); st[3] = f2bf(acc[fm][fn][3]);
            *(short4v*)(Ct + obase + (size_t)n * 1024) = st;
        }
    }
}

// ---------------- bf16 MFMA GEMM 64x64 (for small-N gemm2; 4x grid) ------------
__global__ __launch_bounds__(256) void k_gemm64(
        const short* __restrict__ A, const short* __restrict__ Bt,
        short* __restrict__ Ct, int K, int Ncols) {
    int tid = threadIdx.x, wave = tid >> 6, lane = tid & 63;
    int lr = lane & 15, lg = lane >> 4;
    int flat = blockIdx.y * gridDim.x + blockIdx.x;
    int chunkw = (gridDim.x * gridDim.y) >> 3;
    int swz = (flat & 7) * chunkw + (flat >> 3);
    int bx = swz % gridDim.x, by = swz / gridDim.x;
    int m0 = bx * 64, n0 = by * 64;
    int wm = (wave >> 1) * 32, wn = (wave & 1) * 32;
    __shared__ short lsA[2][64 * 32], lsB[2][64 * 32];
    f32x4 acc[2][2];
#pragma unroll
    for (int i = 0; i < 2; i++)
#pragma unroll
        for (int j = 0; j < 2; j++) acc[i][j] = (f32x4){0.f, 0.f, 0.f, 0.f};

    auto stage = [&](int bufsel, int k0) {
        int r = tid >> 2, c = tid & 3;          // 256 chunks, 1 per thread
        int csrc = c ^ (r & 3);
        int base = (wave * 64) * 8;
        gload_lds16(A + (size_t)(m0 + r) * K + k0 + csrc * 8, &lsA[bufsel][base]);
        gload_lds16(Bt + (size_t)(n0 + r) * K + k0 + csrc * 8, &lsB[bufsel][base]);
    };
    stage(0, 0);
    __syncthreads();
    int buf = 0;
    for (int k0 = 0; k0 < K; k0 += 32) {
        if (k0 + 32 < K) stage(buf ^ 1, k0 + 32);
        short8 a[2], bb[2];
#pragma unroll
        for (int f = 0; f < 2; f++) {
            int ra = wm + f * 16 + lr, rb = wn + f * 16 + lr;
            a[f]  = *(const short8*)(&lsA[buf][ra * 32 + ((lg ^ (ra & 3)) * 8)]);
            bb[f] = *(const short8*)(&lsB[buf][rb * 32 + ((lg ^ (rb & 3)) * 8)]);
        }
#pragma unroll
        for (int fm = 0; fm < 2; fm++)
#pragma unroll
            for (int fn = 0; fn < 2; fn++)
                acc[fm][fn] = __builtin_amdgcn_mfma_f32_16x16x32_bf16(a[fm], bb[fn], acc[fm][fn], 0, 0, 0);
        __syncthreads();
        buf ^= 1;
    }
#pragma unroll
    for (int fm = 0; fm < 2; fm++) {
        int mb = m0 + wm + fm * 16 + lg * 4;
        size_t obase = ((size_t)(mb >> 10) * Ncols) * 1024 + (mb & 1023);
#pragma unroll
        for (int fn = 0; fn < 2; fn++) {
            int n = n0 + wn + fn * 16 + lr;
            short4v st;
            st[0] = f2bf(acc[fm][fn][0]); st[1] = f2bf(acc[fm][fn][1]);
            st[2] = f2bf(acc[fm][fn][2]); st[3] = f2bf(acc[fm][fn][3]);
            *(short4v*)(Ct + obase + (size_t)n * 1024) = st;
        }
    }
}

// ---------------- s1/s2 = h . a1 / h . a2 (reads transposed h: [bh][o][i]) ------
__global__ __launch_bounds__(256) void k_s12(
        const short* __restrict__ ht, const float* __restrict__ a1,
        const float* __restrict__ a2, float* __restrict__ s1,
        float* __restrict__ s2, int nh) {
    int bh = blockIdx.x >> 2;
    int i = ((blockIdx.x & 3) << 8) + threadIdx.x;
    int h = bh % nh;
    const short* base = ht + (size_t)bh * 131072 + i;
    float acc1 = 0.f, acc2 = 0.f;
#pragma unroll 8
    for (int o = 0; o < 128; o++) {
        float v = b2f(base[(size_t)o << 10]);
        acc1 += v * a1[h * 128 + o];
        acc2 += v * a2[h * 128 + o];
    }
    s1[bh * 1024 + i] = acc1;
    s2[bh * 1024 + i] = acc2;
}

// ---------------- per-row softmax stats: c1 = -max - log(sum) ----------------
__global__ __launch_bounds__(256) void k_stats(
        const unsigned* __restrict__ adjb, const float* __restrict__ s1,
        const float* __restrict__ s2, float* __restrict__ c1a, int nh) {
    int w = blockIdx.x * 4 + (threadIdx.x >> 6);
    int lane = threadIdx.x & 63;
    int b = w >> 10, i = w & 1023;
    const unsigned long long* ab =
        (const unsigned long long*)(adjb + ((size_t)(b << 10) + i) * 32);
    unsigned long long aw[16];
#pragma unroll
    for (int jc = 0; jc < 16; jc++) aw[jc] = ab[jc];
    for (int h = 0; h < nh; h++) {
        int bh = b * nh + h;
        float s1i = s1[bh * 1024 + i];
        const float* s2r = s2 + bh * 1024;
        float e[16];
        float m = -3.4e38f;
#pragma unroll
        for (int jc = 0; jc < 16; jc++) {
            float ee = s1i + s2r[jc * 64 + lane];
            ee = fmaxf(ee, ALPHA * ee);
            ee = ((aw[jc] >> lane) & 1) ? ee : NEGF;
            e[jc] = ee;
            m = fmaxf(m, ee);
        }
#pragma unroll
        for (int off = 32; off > 0; off >>= 1) m = fmaxf(m, __shfl_xor(m, off));
        float s = 0.f;
#pragma unroll
        for (int jc = 0; jc < 16; jc++) s += __expf(e[jc] - m);
#pragma unroll
        for (int off = 32; off > 0; off >>= 1) s += __shfl_xor(s, off);
        if (lane == 0) c1a[bh * 1024 + i] = -m - __logf(s);
    }
}

// ---------------- GAT layer-1 attention: 8 waves, 128 i-rows per block ---------
__global__ __launch_bounds__(512) void k_attn1(
        const short* __restrict__ ht, const unsigned* __restrict__ adjb,
        const float* __restrict__ s1, const float* __restrict__ s2,
        const float* __restrict__ c1a, short* __restrict__ out) {
    int bh = blockIdx.y;
    int b = bh >> 3, h = bh & 7;
    int tid = threadIdx.x, wave = tid >> 6, lane = tid & 63;
    int lr = lane & 15, lg = lane >> 4;
    int ic = blockIdx.x * 128 + wave * 16 + lr;
    int row = bh * 1024 + ic;
    float s1i = s1[row], c1i = c1a[row];
    const unsigned long long* abrow =
        (const unsigned long long*)(adjb + ((size_t)(b << 10) + ic) * 32);
    const float* s2r = s2 + bh * 1024;
    const short* hbase = ht + (size_t)bh * 131072;

    __shared__ short lsh[2][8192];   // [128 o][64 j] bf16, chunk-XOR swizzled
    f32x4 acc[8];
#pragma unroll
    for (int f = 0; f < 8; f++) acc[f] = (f32x4){0.f, 0.f, 0.f, 0.f};

    auto stage = [&](int bufsel, int j0) {
#pragma unroll
        for (int s = 0; s < 2; s++) {
            int chunk = s * 512 + tid;       // 0..1023 (16B chunks)
            int r = chunk >> 3, c = chunk & 7;
            int csrc = c ^ (r & 7);          // inverse-swizzle the SOURCE
            gload_lds16(hbase + (size_t)r * 1024 + j0 + csrc * 8,
                        &lsh[bufsel][(s * 512 + wave * 64) * 8]);
        }
    };
    stage(0, 0);
    __syncthreads();
    int buf = 0;
    for (int j0 = 0; j0 < 1024; j0 += 64) {
        if (j0 < 960) stage(buf ^ 1, j0 + 64);
        unsigned long long aw = abrow[j0 >> 6];
#pragma unroll
        for (int kk = 0; kk < 2; kk++) {
            int jb = j0 + kk * 32 + lg * 8;
            f32x4 t0 = *(const f32x4*)(s2r + jb);
            f32x4 t1 = *(const f32x4*)(s2r + jb + 4);
            unsigned bits = (unsigned)(aw >> (kk * 32 + lg * 8)) & 0xFFu;
            float pv[8];
#pragma unroll
            for (int e = 0; e < 8; e++) {
                float sv = e < 4 ? t0[e] : t1[e & 3];
                float ee = s1i + sv;
                ee = fmaxf(ee, ALPHA * ee);
                float p = __expf(ee + c1i);
                pv[e] = ((bits >> e) & 1) ? p : 0.f;
            }
            int4v pw;
#pragma unroll
            for (int w = 0; w < 4; w++) {
                int d;
                asm("v_cvt_pk_bf16_f32 %0, %1, %2"
                    : "=v"(d) : "v"(pv[2 * w]), "v"(pv[2 * w + 1]));
                pw[w] = d;
            }
            short8 pb = __builtin_bit_cast(short8, pw);
#pragma unroll
            for (int fm = 0; fm < 8; fm++) {
                int r = fm * 16 + lr;
                int ck = (kk * 4 + lg) ^ (r & 7);   // swizzled read
                short8 af = *(const short8*)(&lsh[buf][r * 64 + ck * 8]);
                acc[fm] = __builtin_amdgcn_mfma_f32_16x16x32_bf16(af, pb, acc[fm], 0, 0, 0);
            }
        }
        __syncthreads();
        buf ^= 1;
    }
    size_t orow = ((size_t)(b << 10) + ic) * 1024 + h * 128;
#pragma unroll
    for (int fm = 0; fm < 8; fm++) {
        int ob = (fm << 4) + lg * 4;
        short4v st;
#pragma unroll
        for (int r = 0; r < 4; r++) {
            float x = acc[fm][r];
            x = x > 0.f ? x : expm1f(x);
            st[r] = f2bf(x);
        }
        *(short4v*)(out + orow + ob) = st;
    }
}

// ---------------- layer-2 attention, GATHERED rows only (33 per batch) ---------
__global__ __launch_bounds__(256) void k_attn2g(
        const short* __restrict__ h2t, const unsigned* __restrict__ adjb,
        const float* __restrict__ s1, const float* __restrict__ s2,
        const int* __restrict__ cidx, float* __restrict__ ghat) {
    int tile = blockIdx.x;      // 0..2
    int b = blockIdx.y;         // 0..7
    int tid = threadIdx.x, wave = tid >> 6, lane = tid & 63;
    int lr = lane & 15, lg = lane >> 4;

    __shared__ int nodes[16];
    __shared__ float sc1[16];
    __shared__ float sacc[4][16][129];

    if (tid < 16) {
        int pos = tile * 16 + tid;
        int nd = 0;
        if (pos >= 1 && pos <= 32) nd = cidx[b * 32 + pos - 1];
        nodes[tid] = nd;
    }
    __syncthreads();

    const float* s2r = s2 + b * 1024;
    for (int q = 0; q < 4; q++) {
        int li = wave * 4 + q;
        int nd = nodes[li];
        float s1i = s1[b * 1024 + nd];
        const unsigned long long* ab =
            (const unsigned long long*)(adjb + ((size_t)(b << 10) + nd) * 32);
        float ev[16];
        float m = -3.4e38f;
#pragma unroll
        for (int c = 0; c < 16; c++) {
            float ee = s1i + s2r[c * 64 + lane];
            ee = fmaxf(ee, ALPHA * ee);
            ee = ((ab[c] >> lane) & 1) ? ee : NEGF;
            ev[c] = ee;
            m = fmaxf(m, ee);
        }
#pragma unroll
        for (int off = 32; off > 0; off >>= 1) m = fmaxf(m, __shfl_xor(m, off));
        float s = 0.f;
#pragma unroll
        for (int c = 0; c < 16; c++) s += __expf(ev[c] - m);
#pragma unroll
        for (int off = 32; off > 0; off >>= 1) s += __shfl_xor(s, off);
        if (lane == 0) sc1[li] = -m - __logf(s);
    }
    __syncthreads();

    int nd = nodes[lr];
    float s1i = s1[b * 1024 + nd];
    float c1i = sc1[lr];
    const unsigned long long* abrow =
        (const unsigned long long*)(adjb + ((size_t)(b << 10) + nd) * 32);
    const short* hb = h2t + (size_t)b * 131072;
    f32x4 acc[8];
#pragma unroll
    for (int f = 0; f < 8; f++) acc[f] = (f32x4){0.f, 0.f, 0.f, 0.f};

    for (int j0 = wave * 256; j0 < wave * 256 + 256; j0 += 32) {
        int jb = j0 + lg * 8;
        f32x4 t0 = *(const f32x4*)(s2r + jb);
        f32x4 t1 = *(const f32x4*)(s2r + jb + 4);
        unsigned bits = (unsigned)(abrow[j0 >> 6] >> ((j0 & 32) + lg * 8)) & 0xFFu;
        short8 pb;
#pragma unroll
        for (int e = 0; e < 8; e++) {
            float sv = e < 4 ? t0[e] : t1[e & 3];
            float ee = s1i + sv;
            ee = fmaxf(ee, ALPHA * ee);
            float p = __expf(ee + c1i);
            p = ((bits >> e) & 1) ? p : 0.f;
            pb[e] = f2bf(p);
        }
#pragma unroll
        for (int fm = 0; fm < 8; fm++) {
            short8 af = *(const short8*)(hb + (size_t)(fm * 16 + lr) * 1024 + jb);
            acc[fm] = __builtin_amdgcn_mfma_f32_16x16x32_bf16(af, pb, acc[fm], 0, 0, 0);
        }
    }
#pragma unroll
    for (int fm = 0; fm < 8; fm++)
#pragma unroll
        for (int r = 0; r < 4; r++)
            sacc[wave][lr][fm * 16 + lg * 4 + r] = acc[fm][r];
    __syncthreads();
    for (int e = tid; e < 2048; e += 256) {
        int li = e >> 7, o = e & 127;
        float v = sacc[0][li][o] + sacc[1][li][o] + sacc[2][li][o] + sacc[3][li][o];
        v = v > 0.f ? v : expm1f(v);
        ghat[((size_t)b * 48 + tile * 16 + li) * 128 + o] = v;
    }
}

// ---------------- K/V projections, gload_lds-staged weight slices --------------
// grid (16, 8): bx&7 = row-group (4 ctx rows), bx>>3 = o-half (64 cols)
__global__ __launch_bounds__(256) void k_qkv(
        const float* __restrict__ ghat,
        const float* __restrict__ wk, const float* __restrict__ bk,
        const float* __restrict__ wvp, const float* __restrict__ bv,
        float* __restrict__ Kp, float* __restrict__ Vp) {
    int b = blockIdx.y, rg = blockIdx.x & 7, o0 = (blockIdx.x >> 3) * 64;
    int t = threadIdx.x, wvi = t >> 6, ln = t & 63;
    __shared__ float sx[4][128];
    __shared__ float sWk[128 * 64], sWv[128 * 64];

    // sx: 512 floats = 128 chunks (ghat rows contiguous), waves 0-1
    if (wvi < 2) {
        int cb = wvi * 64;
        gload_lds16(ghat + ((size_t)b * 48 + 1 + rg * 4) * 128 + (size_t)(cb + ln) * 4,
                    (float*)sx + cb * 4);
    }
    // weight slices: 8192 floats = 2048 chunks each; chunk q: rw=q>>4, c4=q&15
#pragma unroll
    for (int s = 0; s < 8; s++) {
        int cb = s * 256 + wvi * 64;
        int q = cb + ln, rw = q >> 4, c4 = q & 15;
        gload_lds16(wk  + (size_t)rw * 128 + o0 + c4 * 4, &sWk[cb * 4]);
        gload_lds16(wvp + (size_t)rw * 128 + o0 + c4 * 4, &sWv[cb * 4]);
    }
    __syncthreads();
    int o = o0 + ln;                            // wvi = ctx row (0..3)
    float ka = bk[o], va = bv[o];
#pragma unroll 32
    for (int c = 0; c < 128; c++) {
        float x = sx[wvi][c];
        ka += x * sWk[c * 64 + ln];
        va += x * sWv[c * 64 + ln];
    }
    int r = rg * 4 + wvi;
    Kp[((size_t)b * 32 + r) * 128 + o] = ka;
    Vp[((size_t)b * 32 + r) * 128 + o] = va;
}

// ---------------- tail: Qproj + MHA + wo + p1 + LN + relu -> tvec --------------
__global__ __launch_bounds__(256) void k_tail(
        const float* __restrict__ ghat, const float* __restrict__ Kp,
        const float* __restrict__ Vp,
        const float* __restrict__ wq, const float* __restrict__ bq,
        const float* __restrict__ wo, const float* __restrict__ bo,
        const float* __restrict__ p1w, const float* __restrict__ p1b,
        const float* __restrict__ lng, const float* __restrict__ lnb,
        float* __restrict__ tvec) {
    int b = blockIdx.x, t = threadIdx.x;
    int wvi = t >> 6, ln = t & 63;
    __shared__ float sq[128], sQ[128], sK[32][128], sV[32][128];
    __shared__ float sP[4][33], sO[128], sT[128], sZ[128];
    __shared__ float sred[2];
    __shared__ float sW[128 * 128];   // 64KB staged-weight buffer (reused)

    // phase 1: async-stage K, V (1024 chunks each, contiguous) + wq (4096 chunks)
#pragma unroll
    for (int s = 0; s < 4; s++) {
        int cb = s * 256 + wvi * 64;
        gload_lds16(Kp + (size_t)b * 4096 + (size_t)(cb + ln) * 4, (float*)sK + cb * 4);
        gload_lds16(Vp + (size_t)b * 4096 + (size_t)(cb + ln) * 4, (float*)sV + cb * 4);
    }
#pragma unroll
    for (int s = 0; s < 16; s++) {
        int cb = s * 256 + wvi * 64;
        gload_lds16(wq + (size_t)(cb + ln) * 4, &sW[cb * 4]);
    }
    if (t < 128) sq[t] = ghat[(size_t)b * 48 * 128 + t];
    __syncthreads();                 // drains vmcnt
    // phase 2: Q projection from LDS
    if (t < 128) {
        float a0 = 0.f, a1 = 0.f, a2 = 0.f, a3 = 0.f;
#pragma unroll
        for (int c = 0; c < 128; c += 4) {
            a0 += sq[c]     * sW[c * 128 + t];
            a1 += sq[c + 1] * sW[(c + 1) * 128 + t];
            a2 += sq[c + 2] * sW[(c + 2) * 128 + t];
            a3 += sq[c + 3] * sW[(c + 3) * 128 + t];
        }
        sQ[t] = bq[t] + ((a0 + a1) + (a2 + a3));
    }
    __syncthreads();
    // phase 3: issue wo staging; scores + softmax meanwhile
#pragma unroll
    for (int s = 0; s < 16; s++) {
        int cb = s * 256 + wvi * 64;
        gload_lds16(wo + (size_t)(cb + ln) * 4, &sW[cb * 4]);
    }
    if (t < 128) {
        int hh = t >> 5, jj = t & 31;
        float s = 0.f;
#pragma unroll
        for (int d = 0; d < 32; d++) s += sQ[hh * 32 + d] * sK[jj][hh * 32 + d];
        s *= 0.17677669529663687f;   // 1/sqrt(32)
        float m = s;
#pragma unroll
        for (int off = 16; off > 0; off >>= 1) m = fmaxf(m, __shfl_xor(m, off, 32));
        float p = __expf(s - m);
        float sum = p;
#pragma unroll
        for (int off = 16; off > 0; off >>= 1) sum += __shfl_xor(sum, off, 32);
        sP[hh][jj] = p / sum;
    }
    __syncthreads();
    // phase 4: PV
    if (t < 128) {
        int hh = t >> 5;
        float s = 0.f;
#pragma unroll
        for (int jj = 0; jj < 32; jj++) s += sP[hh][jj] * sV[jj][t];
        sO[t] = s;
    }
    __syncthreads();
    // phase 5: wo GEMV
    if (t < 128) {
        float a0 = 0.f, a1 = 0.f, a2 = 0.f, a3 = 0.f;
#pragma unroll
        for (int c = 0; c < 128; c += 4) {
            a0 += sO[c]     * sW[c * 128 + t];
            a1 += sO[c + 1] * sW[(c + 1) * 128 + t];
            a2 += sO[c + 2] * sW[(c + 2) * 128 + t];
            a3 += sO[c + 3] * sW[(c + 3) * 128 + t];
        }
        sT[t] = bo[t] + ((a0 + a1) + (a2 + a3));
    }
    __syncthreads();
    // phase 6: stage p1w (async, one round)
#pragma unroll
    for (int s = 0; s < 16; s++) {
        int cb = s * 256 + wvi * 64;
        gload_lds16(p1w + (size_t)(cb + ln) * 4, &sW[cb * 4]);
    }
    __syncthreads();
    // phase 7: p1 GEMV
    if (t < 128) {
        float a0 = 0.f, a1 = 0.f, a2 = 0.f, a3 = 0.f;
#pragma unroll
        for (int c = 0; c < 128; c += 4) {
            a0 += sT[c]     * sW[c * 128 + t];
            a1 += sT[c + 1] * sW[(c + 1) * 128 + t];
            a2 += sT[c + 2] * sW[(c + 2) * 128 + t];
            a3 += sT[c + 3] * sW[(c + 3) * 128 + t];
        }
        sZ[t] = p1b[t] + ((a0 + a1) + (a2 + a3));
    }
    __syncthreads();
    // phase 8: LayerNorm + ReLU -> tvec
    if (t < 64) {
        float v = sZ[t] + sZ[t + 64];
#pragma unroll
        for (int off = 32; off > 0; off >>= 1) v += __shfl_xor(v, off);
        if (t == 0) sred[0] = v * (1.f / 128.f);
    }
    __syncthreads();
    float mu = sred[0];
    if (t < 64) {
        float d1 = sZ[t] - mu, d2 = sZ[t + 64] - mu;
        float v = d1 * d1 + d2 * d2;
#pragma unroll
        for (int off = 32; off > 0; off >>= 1) v += __shfl_xor(v, off);
        if (t == 0) sred[1] = v * (1.f / 128.f);
    }
    __syncthreads();
    float rstd = rsqrtf(sred[1] + 1e-5f);
    if (t < 128) {
        float z = (sZ[t] - mu) * rstd * lng[t] + lnb[t];
        tvec[b * 128 + t] = fmaxf(z, 0.f);
    }
}

// ---------------- p2 projection: 48 blocks, gload_lds weight tiles -------------
// grid (6, 8): bx = 128-col tile of p2w, by = batch
__global__ __launch_bounds__(256) void k_p2(
        const float* __restrict__ tvec, const float* __restrict__ p2w,
        const float* __restrict__ p2b, float* __restrict__ out) {
    int jj0 = blockIdx.x * 128, b = blockIdx.y;
    int t = threadIdx.x, wvi = t >> 6, ln = t & 63;
    __shared__ float sT[128];
    __shared__ float sW[128 * 128];   // [c][jj] tile

    // 4096 chunks; chunk q: c = q>>5, c4 = q&31 (per-lane global addr)
#pragma unroll
    for (int s = 0; s < 16; s++) {
        int cb = s * 256 + wvi * 64;
        int q = cb + ln, c = q >> 5, c4 = q & 31;
        gload_lds16(p2w + (size_t)c * 768 + jj0 + c4 * 4, &sW[cb * 4]);
    }
    if (t < 128) sT[t] = tvec[b * 128 + t];
    __syncthreads();
    if (t < 128) {
        float a0 = 0.f, a1 = 0.f, a2 = 0.f, a3 = 0.f;
#pragma unroll
        for (int c = 0; c < 128; c += 4) {
            a0 += sT[c]     * sW[c * 128 + t];
            a1 += sT[c + 1] * sW[(c + 1) * 128 + t];
            a2 += sT[c + 2] * sW[(c + 2) * 128 + t];
            a3 += sT[c + 3] * sW[(c + 3) * 128 + t];
        }
        out[b * 768 + jj0 + t] = p2b[jj0 + t] + ((a0 + a1) + (a2 + a3));
    }
}

extern "C" void kernel_launch(void* const* d_in, const int* in_sizes, int n_in,
                              void* d_out, int out_size, void* d_ws, size_t ws_size,
                              hipStream_t stream) {
    const float* x   = (const float*)d_in[0];
    const int*  adj  = (const int*)d_in[1];
    const int*  cidx = (const int*)d_in[2];
    const float* W1  = (const float*)d_in[3];
    const float* a11 = (const float*)d_in[4];
    const float* a21 = (const float*)d_in[5];
    const float* W2  = (const float*)d_in[6];
    const float* a12 = (const float*)d_in[7];
    const float* a22 = (const float*)d_in[8];
    const float* wq = (const float*)d_in[9];  const float* bq = (const float*)d_in[10];
    const float* wk = (const float*)d_in[11]; const float* bk = (const float*)d_in[12];
    const float* wv = (const float*)d_in[13]; const float* bv = (const float*)d_in[14];
    const float* wo = (const float*)d_in[15]; const float* bo = (const float*)d_in[16];
    const float* p1w = (const float*)d_in[17]; const float* p1b = (const float*)d_in[18];
    const float* lng = (const float*)d_in[19]; const float* lnb = (const float*)d_in[20];
    const float* p2w = (const float*)d_in[21]; const float* p2b = (const float*)d_in[22];
    float* out = (float*)d_out;

    char* ws = (char*)d_ws;
    size_t off = 0;
    auto alloc = [&](size_t bytes) -> char* {
        char* p = ws + off;
        off = (off + bytes + 255) & ~(size_t)255;
        return p;
    };
    short* Xb   = (short*)alloc(8192ull * 768 * 2);
    short* W1T  = (short*)alloc(1024ull * 768 * 2);
    short* W2T  = (short*)alloc(128ull * 1024 * 2);
    unsigned* adjb = (unsigned*)alloc(8ull * 1024 * 32 * 4);
    short* h1t  = (short*)alloc(64ull * 128 * 1024 * 2);
    float* s1a  = (float*)alloc(64ull * 1024 * 4);
    float* s2a  = (float*)alloc(64ull * 1024 * 4);
    float* c1a  = (float*)alloc(64ull * 1024 * 4);
    short* hcat = (short*)alloc(8192ull * 1024 * 2);
    short* h2t  = (short*)alloc(8ull * 128 * 1024 * 2);
    float* s1b  = (float*)alloc(8192ull * 4);
    float* s2b  = (float*)alloc(8192ull * 4);
    float* ghat = (float*)alloc(8ull * 48 * 128 * 4);
    float* Kp   = (float*)alloc(8ull * 32 * 128 * 4);
    float* Vp   = (float*)alloc(8ull * 32 * 128 * 4);
    float* tvec = (float*)alloc(8ull * 128 * 4);
    if (off > ws_size) return;

    k_cast_x<<<6144, 256, 0, stream>>>(x, Xb, 1572864);
    k_w1t<<<3072, 256, 0, stream>>>(W1, W1T);
    k_w2t<<<512, 256, 0, stream>>>(W2, W2T);
    k_adjbits<<<32768, 256, 0, stream>>>(adj, adjb);

    // layer 1
    k_gemm_bt<<<dim3(64, 8), 256, 0, stream>>>(Xb, W1T, h1t, 768, 1024);
    k_s12<<<256, 256, 0, stream>>>(h1t, a11, a21, s1a, s2a, 8);
    k_stats<<<2048, 256, 0, stream>>>(adjb, s1a, s2a, c1a, 8);
    k_attn1<<<dim3(8, 64), 512, 0, stream>>>(h1t, adjb, s1a, s2a, c1a, hcat);

    // layer 2 (GEMM full; attention only for gathered rows)
    k_gemm64<<<dim3(128, 2), 256, 0, stream>>>(hcat, W2T, h2t, 1024, 128);
    k_s12<<<32, 256, 0, stream>>>(h2t, a12, a22, s1b, s2b, 1);
    k_attn2g<<<dim3(3, 8), 256, 0, stream>>>(h2t, adjb, s1b, s2b, cidx, ghat);

    // tail
    k_qkv<<<dim3(16, 8), 256, 0, stream>>>(ghat, wk, bk, wv, bv, Kp, Vp);
    k_tail<<<8, 256, 0, stream>>>(ghat, Kp, Vp, wq, bq, wo, bo,
                                  p1w, p1b, lng, lnb, tvec);
    k_p2<<<dim3(6, 8), 256, 0, stream>>>(tvec, p2w, p2b, out);
}

// Round 9
// 161.034 us; speedup vs baseline: 1.5678x; 1.1983x over previous
//
#include <hip/hip_runtime.h>
#include <hip/hip_bf16.h>

#define ALPHA 0.2f
#define LOG2E 1.4426950408889634f

using short8  = __attribute__((ext_vector_type(8))) short;
using short4v = __attribute__((ext_vector_type(4))) short;
using f32x4   = __attribute__((ext_vector_type(4))) float;
using int4v   = __attribute__((ext_vector_type(4))) int;

static __device__ __forceinline__ float b2f(short s) {
    union { float f; unsigned u; } v; v.u = ((unsigned)(unsigned short)s) << 16; return v.f;
}
static __device__ __forceinline__ short f2bf(float f) {
    __hip_bfloat16 h = __float2bfloat16(f);
    return *reinterpret_cast<short*>(&h);
}
static __device__ __forceinline__ float fexp2(float x) {
    return __builtin_amdgcn_exp2f(x);          // v_exp_f32: D = 2^S0
}
static __device__ __forceinline__ void gload_lds16(const void* g, void* l) {
    __builtin_amdgcn_global_load_lds(
        (const __attribute__((address_space(1))) unsigned*)g,
        (__attribute__((address_space(3))) unsigned*)l, 16, 0, 0);
}

// ---------------- fused prep: adjbits | cast_x | w1t | w2t ----------------------
__global__ __launch_bounds__(256) void k_prep(
        const int* __restrict__ adj, unsigned* __restrict__ adjb,
        const float* __restrict__ x, short* __restrict__ xb,
        const float* __restrict__ W1, short* __restrict__ W1T,
        const float* __restrict__ W2, short* __restrict__ W2T) {
    int bid = blockIdx.x, t = threadIdx.x;
    if (bid < 32768) {                       // adj int32 -> bit-packed
        int idx = bid * 256 + t;
        int lane = t & 63;
        unsigned long long m = __ballot(adj[idx] > 0);
        if ((lane & 31) == 0) adjb[idx >> 5] = (unsigned)(m >> (lane & 32));
    } else if (bid < 38912) {                // x f32 -> bf16 (x4)
        int idx = (bid - 32768) * 256 + t;
        f32x4 v = ((const f32x4*)x)[idx];
        short4v o;
        o[0] = f2bf(v[0]); o[1] = f2bf(v[1]); o[2] = f2bf(v[2]); o[3] = f2bf(v[3]);
        ((short4v*)xb)[idx] = o;
    } else if (bid < 41984) {                // W1T[n][k] = W1[h][k][o]
        int idx = (bid - 38912) * 256 + t;
        int n = idx / 768, k = idx - n * 768;
        int h = n >> 7, o = n & 127;
        W1T[idx] = f2bf(W1[(h * 768 + k) * 128 + o]);
    } else {                                 // W2T[n][k] = W2[0][k][n]
        int idx = (bid - 41984) * 256 + t;
        int n = idx >> 10, k = idx & 1023;
        W2T[idx] = f2bf(W2[k * 128 + n]);
    }
}

// ---------------- bf16 MFMA GEMM 128x128, BK=64, pair-unrolled, XCD-swz --------
__global__ __launch_bounds__(256) void k_gemm_bt(
        const short* __restrict__ A, const short* __restrict__ Bt,
        short* __restrict__ Ct, int K, int Ncols) {
    int tid = threadIdx.x, wave = tid >> 6, lane = tid & 63;
    int lr = lane & 15, lg = lane >> 4;
    int flat = blockIdx.y * gridDim.x + blockIdx.x;
    int chunkw = (gridDim.x * gridDim.y) >> 3;
    int swz = (flat & 7) * chunkw + (flat >> 3);
    int bx = swz % gridDim.x, by = swz / gridDim.x;
    int m0 = bx * 128, n0 = by * 128;
    int wm = (wave >> 1) * 64, wn = (wave & 1) * 64;
    __shared__ short lsA[2][128 * 64], lsB[2][128 * 64];
    f32x4 acc[4][4];
#pragma unroll
    for (int i = 0; i < 4; i++)
#pragma unroll
        for (int j = 0; j < 4; j++) acc[i][j] = (f32x4){0.f, 0.f, 0.f, 0.f};

    auto stage = [&](int bufsel, int k0) {
#pragma unroll
        for (int s = 0; s < 4; s++) {
            int chunk = s * 256 + tid;          // 1024 chunks of 16B per matrix
            int r = chunk >> 3, c = chunk & 7;
            int csrc = c ^ (r & 7);             // inverse-swizzled source
            gload_lds16(A + (size_t)(m0 + r) * K + k0 + csrc * 8, &lsA[bufsel][chunk * 8]);
            gload_lds16(Bt + (size_t)(n0 + r) * K + k0 + csrc * 8, &lsB[bufsel][chunk * 8]);
        }
    };
    auto compute = [&](const short* la, const short* lb) {
#pragma unroll
        for (int kk = 0; kk < 2; kk++) {
            short8 a[4], bb[4];
#pragma unroll
            for (int f = 0; f < 4; f++) {
                int ra = wm + f * 16 + lr, rb = wn + f * 16 + lr;
                a[f]  = *(const short8*)(la + ra * 64 + (((kk * 4 + lg) ^ (ra & 7)) * 8));
                bb[f] = *(const short8*)(lb + rb * 64 + (((kk * 4 + lg) ^ (rb & 7)) * 8));
            }
#pragma unroll
            for (int fm = 0; fm < 4; fm++)
#pragma unroll
                for (int fn = 0; fn < 4; fn++)
                    acc[fm][fn] = __builtin_amdgcn_mfma_f32_16x16x32_bf16(a[fm], bb[fn], acc[fm][fn], 0, 0, 0);
        }
    };
    stage(0, 0);
    __syncthreads();
    for (int k2 = 0; k2 < K; k2 += 128) {       // requires K % 128 == 0
        stage(1, k2 + 64);
        compute(lsA[0], lsB[0]);
        __syncthreads();
        if (k2 + 128 < K) stage(0, k2 + 128);
        compute(lsA[1], lsB[1]);
        __syncthreads();
    }
#pragma unroll
    for (int fm = 0; fm < 4; fm++) {
        int mb = m0 + wm + fm * 16 + lg * 4;
        size_t obase = ((size_t)(mb >> 10) * Ncols) * 1024 + (mb & 1023);
#pragma unroll
        for (int fn = 0; fn < 4; fn++) {
            int n = n0 + wn + fn * 16 + lr;
            short4v st;
            st[0] = f2bf(acc[fm][fn][0]); st[1] = f2bf(acc[fm][fn][1]);
            st[2] = f2bf(acc[fm][fn][2]); st[3] = f2bf(acc[fm][fn][3]);
            *(short4v*)(Ct + obase + (size_t)n * 1024) = st;
        }
    }
}

// ---------------- bf16 MFMA GEMM 64x64 (layer-2; unchanged structure) ----------
__global__ __launch_bounds__(256) void k_gemm64(
        const short* __restrict__ A, const short* __restrict__ Bt,
        short* __restrict__ Ct, int K, int Ncols) {
    int tid = threadIdx.x, wave = tid >> 6, lane = tid & 63;
    int lr = lane & 15, lg = lane >> 4;
    int flat = blockIdx.y * gridDim.x + blockIdx.x;
    int chunkw = (gridDim.x * gridDim.y) >> 3;
    int swz = (flat & 7) * chunkw + (flat >> 3);
    int bx = swz % gridDim.x, by = swz / gridDim.x;
    int m0 = bx * 64, n0 = by * 64;
    int wm = (wave >> 1) * 32, wn = (wave & 1) * 32;
    __shared__ short lsA[2][64 * 32], lsB[2][64 * 32];
    f32x4 acc[2][2];
#pragma unroll
    for (int i = 0; i < 2; i++)
#pragma unroll
        for (int j = 0; j < 2; j++) acc[i][j] = (f32x4){0.f, 0.f, 0.f, 0.f};

    auto stage = [&](int bufsel, int k0) {
        int r = tid >> 2, c = tid & 3;
        int csrc = c ^ (r & 3);
        int base = (wave * 64) * 8;
        gload_lds16(A + (size_t)(m0 + r) * K + k0 + csrc * 8, &lsA[bufsel][base]);
        gload_lds16(Bt + (size_t)(n0 + r) * K + k0 + csrc * 8, &lsB[bufsel][base]);
    };
    stage(0, 0);
    __syncthreads();
    int buf = 0;
    for (int k0 = 0; k0 < K; k0 += 32) {
        if (k0 + 32 < K) stage(buf ^ 1, k0 + 32);
        short8 a[2], bb[2];
#pragma unroll
        for (int f = 0; f < 2; f++) {
            int ra = wm + f * 16 + lr, rb = wn + f * 16 + lr;
            a[f]  = *(const short8*)(&lsA[buf][ra * 32 + ((lg ^ (ra & 3)) * 8)]);
            bb[f] = *(const short8*)(&lsB[buf][rb * 32 + ((lg ^ (rb & 3)) * 8)]);
        }
#pragma unroll
        for (int fm = 0; fm < 2; fm++)
#pragma unroll
            for (int fn = 0; fn < 2; fn++)
                acc[fm][fn] = __builtin_amdgcn_mfma_f32_16x16x32_bf16(a[fm], bb[fn], acc[fm][fn], 0, 0, 0);
        __syncthreads();
        buf ^= 1;
    }
#pragma unroll
    for (int fm = 0; fm < 2; fm++) {
        int mb = m0 + wm + fm * 16 + lg * 4;
        size_t obase = ((size_t)(mb >> 10) * Ncols) * 1024 + (mb & 1023);
#pragma unroll
        for (int fn = 0; fn < 2; fn++) {
            int n = n0 + wn + fn * 16 + lr;
            short4v st;
            st[0] = f2bf(acc[fm][fn][0]); st[1] = f2bf(acc[fm][fn][1]);
            st[2] = f2bf(acc[fm][fn][2]); st[3] = f2bf(acc[fm][fn][3]);
            *(short4v*)(Ct + obase + (size_t)n * 1024) = st;
        }
    }
}

// ---------------- s1/s2 = (h.a1, h.a2) * log2e, vectorized 4 i/thread ----------
__global__ __launch_bounds__(256) void k_s12(
        const short* __restrict__ ht, const float* __restrict__ a1,
        const float* __restrict__ a2, float* __restrict__ s1,
        float* __restrict__ s2, int nh) {
    int bh = blockIdx.x;
    int h = bh % nh;
    int i4 = threadIdx.x * 4;
    const short* base = ht + (size_t)bh * 131072 + i4;
    f32x4 acc1 = {0.f, 0.f, 0.f, 0.f}, acc2 = {0.f, 0.f, 0.f, 0.f};
#pragma unroll 8
    for (int o = 0; o < 128; o++) {
        short4v v = *(const short4v*)(base + ((size_t)o << 10));
        float w1 = a1[h * 128 + o], w2 = a2[h * 128 + o];
#pragma unroll
        for (int r = 0; r < 4; r++) {
            float f = b2f(v[r]);
            acc1[r] += f * w1;
            acc2[r] += f * w2;
        }
    }
#pragma unroll
    for (int r = 0; r < 4; r++) { acc1[r] *= LOG2E; acc2[r] *= LOG2E; }
    *(f32x4*)(s1 + bh * 1024 + i4) = acc1;
    *(f32x4*)(s2 + bh * 1024 + i4) = acc2;
}

// ---------------- GAT layer-1 attention: unnormalized exp2 + epilogue norm -----
// grid (8, 64) XCD-swizzled so each XCD owns 8 whole bh panels (L2-resident h).
__global__ __launch_bounds__(512) void k_attn1(
        const short* __restrict__ ht, const unsigned* __restrict__ adjb,
        const float* __restrict__ s1, const float* __restrict__ s2,
        short* __restrict__ out) {
    int flat = blockIdx.y * 8 + blockIdx.x;
    int swz = (flat & 7) * 64 + (flat >> 3);    // 512 blocks: bijective
    int bh = swz >> 3, bxi = swz & 7;
    int b = bh >> 3, h = bh & 7;
    int tid = threadIdx.x, wave = tid >> 6, lane = tid & 63;
    int lr = lane & 15, lg = lane >> 4;
    int ic = bxi * 128 + wave * 16 + lr;
    int row = bh * 1024 + ic;
    float s1i = s1[row];                        // pre-scaled by log2e
    const unsigned long long* abrow =
        (const unsigned long long*)(adjb + ((size_t)(b << 10) + ic) * 32);
    const float* s2r = s2 + bh * 1024;
    const short* hbase = ht + (size_t)bh * 131072;

    __shared__ short lsh[2][16384];   // [128 o][128 j] bf16, chunk-XOR swizzled
    f32x4 acc[8];
#pragma unroll
    for (int f = 0; f < 8; f++) acc[f] = (f32x4){0.f, 0.f, 0.f, 0.f};
    float psum = 0.f;

    auto stage = [&](int bufsel, int j0) {
#pragma unroll
        for (int s = 0; s < 4; s++) {
            int chunk = s * 512 + tid;       // 2048 chunks of 16B
            int r = chunk >> 4, c = chunk & 15;
            int csrc = c ^ (r & 15);         // inverse-swizzle the SOURCE
            gload_lds16(hbase + (size_t)r * 1024 + j0 + csrc * 8,
                        &lsh[bufsel][chunk * 8]);
        }
    };
    auto compute = [&](const short* ls, int j0) {
        unsigned long long aw0 = abrow[j0 >> 6], aw1 = abrow[(j0 >> 6) + 1];
#pragma unroll
        for (int kk = 0; kk < 4; kk++) {
            int jb = j0 + kk * 32 + lg * 8;
            f32x4 t0 = *(const f32x4*)(s2r + jb);
            f32x4 t1 = *(const f32x4*)(s2r + jb + 4);
            unsigned long long aw = (kk < 2) ? aw0 : aw1;
            unsigned bits = (unsigned)(aw >> ((kk & 1) * 32 + lg * 8)) & 0xFFu;
            float pv[8];
#pragma unroll
            for (int e = 0; e < 8; e++) {
                float sv = e < 4 ? t0[e] : t1[e & 3];
                float ee = s1i + sv;
                ee = fmaxf(ee, ALPHA * ee);
                float p = fexp2(ee);
                p = ((bits >> e) & 1) ? p : 0.f;
                pv[e] = p;
                psum += p;
            }
            int4v pw;
#pragma unroll
            for (int w = 0; w < 4; w++) {
                int d;
                asm("v_cvt_pk_bf16_f32 %0, %1, %2"
                    : "=v"(d) : "v"(pv[2 * w]), "v"(pv[2 * w + 1]));
                pw[w] = d;
            }
            short8 pb = __builtin_bit_cast(short8, pw);
#pragma unroll
            for (int fm = 0; fm < 8; fm++) {
                int r = fm * 16 + lr;
                int ck = (kk * 4 + lg) ^ (r & 15);   // swizzled read
                short8 af = *(const short8*)(ls + r * 128 + ck * 8);
                acc[fm] = __builtin_amdgcn_mfma_f32_16x16x32_bf16(af, pb, acc[fm], 0, 0, 0);
            }
        }
    };

    stage(0, 0);
    __syncthreads();
    for (int t2 = 0; t2 < 1024; t2 += 256) {
        stage(1, t2 + 128);
        compute(lsh[0], t2);
        __syncthreads();
        if (t2 + 256 < 1024) stage(0, t2 + 256);
        compute(lsh[1], t2 + 128);
        __syncthreads();
    }
    // row-sum: combine the 4 lg-groups holding the same i-row
    psum += __shfl_xor(psum, 16);
    psum += __shfl_xor(psum, 32);
    float rdi = 1.f / psum;
    size_t orow = ((size_t)(b << 10) + ic) * 1024 + h * 128;
#pragma unroll
    for (int fm = 0; fm < 8; fm++) {
        int ob = (fm << 4) + lg * 4;
        short4v st;
#pragma unroll
        for (int r = 0; r < 4; r++) {
            float x = acc[fm][r] * rdi;
            x = x > 0.f ? x : expm1f(x);
            st[r] = f2bf(x);
        }
        *(short4v*)(out + orow + ob) = st;
    }
}

// ---------------- layer-2 attention, GATHERED rows, unnormalized + norm --------
__global__ __launch_bounds__(256) void k_attn2g(
        const short* __restrict__ h2t, const unsigned* __restrict__ adjb,
        const float* __restrict__ s1, const float* __restrict__ s2,
        const int* __restrict__ cidx, float* __restrict__ ghat) {
    int tile = blockIdx.x;      // 0..2
    int b = blockIdx.y;         // 0..7
    int tid = threadIdx.x, wave = tid >> 6, lane = tid & 63;
    int lr = lane & 15, lg = lane >> 4;

    __shared__ int nodes[16];
    __shared__ float sps[4][16];
    __shared__ float sacc[4][16][129];

    if (tid < 16) {
        int pos = tile * 16 + tid;
        int nd = 0;
        if (pos >= 1 && pos <= 32) nd = cidx[b * 32 + pos - 1];
        nodes[tid] = nd;
    }
    __syncthreads();

    const float* s2r = s2 + b * 1024;
    int nd = nodes[lr];
    float s1i = s1[b * 1024 + nd];             // pre-scaled by log2e
    const unsigned long long* abrow =
        (const unsigned long long*)(adjb + ((size_t)(b << 10) + nd) * 32);
    const short* hb = h2t + (size_t)b * 131072;
    f32x4 acc[8];
#pragma unroll
    for (int f = 0; f < 8; f++) acc[f] = (f32x4){0.f, 0.f, 0.f, 0.f};
    float psum = 0.f;

    for (int j0 = wave * 256; j0 < wave * 256 + 256; j0 += 32) {
        int jb = j0 + lg * 8;
        f32x4 t0 = *(const f32x4*)(s2r + jb);
        f32x4 t1 = *(const f32x4*)(s2r + jb + 4);
        unsigned bits = (unsigned)(abrow[j0 >> 6] >> ((j0 & 32) + lg * 8)) & 0xFFu;
        short8 pb;
#pragma unroll
        for (int e = 0; e < 8; e++) {
            float sv = e < 4 ? t0[e] : t1[e & 3];
            float ee = s1i + sv;
            ee = fmaxf(ee, ALPHA * ee);
            float p = fexp2(ee);
            p = ((bits >> e) & 1) ? p : 0.f;
            psum += p;
            pb[e] = f2bf(p);
        }
#pragma unroll
        for (int fm = 0; fm < 8; fm++) {
            short8 af = *(const short8*)(hb + (size_t)(fm * 16 + lr) * 1024 + jb);
            acc[fm] = __builtin_amdgcn_mfma_f32_16x16x32_bf16(af, pb, acc[fm], 0, 0, 0);
        }
    }
    psum += __shfl_xor(psum, 16);
    psum += __shfl_xor(psum, 32);
    if (lg == 0) sps[wave][lr] = psum;
#pragma unroll
    for (int fm = 0; fm < 8; fm++)
#pragma unroll
        for (int r = 0; r < 4; r++)
            sacc[wave][lr][fm * 16 + lg * 4 + r] = acc[fm][r];
    __syncthreads();
    for (int e = tid; e < 2048; e += 256) {
        int li = e >> 7, o = e & 127;
        float sum = sps[0][li] + sps[1][li] + sps[2][li] + sps[3][li];
        float v = (sacc[0][li][o] + sacc[1][li][o] + sacc[2][li][o] + sacc[3][li][o]) / sum;
        v = v > 0.f ? v : expm1f(v);
        ghat[((size_t)b * 48 + tile * 16 + li) * 128 + o] = v;
    }
}

// ---------------- K/V projections, gload_lds-staged weight slices --------------
__global__ __launch_bounds__(256) void k_qkv(
        const float* __restrict__ ghat,
        const float* __restrict__ wk, const float* __restrict__ bk,
        const float* __restrict__ wvp, const float* __restrict__ bv,
        float* __restrict__ Kp, float* __restrict__ Vp) {
    int b = blockIdx.y, rg = blockIdx.x & 7, o0 = (blockIdx.x >> 3) * 64;
    int t = threadIdx.x, wvi = t >> 6, ln = t & 63;
    __shared__ float sx[4][128];
    __shared__ float sWk[128 * 64], sWv[128 * 64];

    if (wvi < 2) {
        int cb = wvi * 64;
        gload_lds16(ghat + ((size_t)b * 48 + 1 + rg * 4) * 128 + (size_t)(cb + ln) * 4,
                    (float*)sx + cb * 4);
    }
#pragma unroll
    for (int s = 0; s < 8; s++) {
        int cb = s * 256 + wvi * 64;
        int q = cb + ln, rw = q >> 4, c4 = q & 15;
        gload_lds16(wk  + (size_t)rw * 128 + o0 + c4 * 4, &sWk[cb * 4]);
        gload_lds16(wvp + (size_t)rw * 128 + o0 + c4 * 4, &sWv[cb * 4]);
    }
    __syncthreads();
    int o = o0 + ln;
    float ka = bk[o], va = bv[o];
#pragma unroll 32
    for (int c = 0; c < 128; c++) {
        float x = sx[wvi][c];
        ka += x * sWk[c * 64 + ln];
        va += x * sWv[c * 64 + ln];
    }
    int r = rg * 4 + wvi;
    Kp[((size_t)b * 32 + r) * 128 + o] = ka;
    Vp[((size_t)b * 32 + r) * 128 + o] = va;
}

// ---------------- tail: Qproj + MHA + wo + p1 + LN + relu -> tvec --------------
__global__ __launch_bounds__(256) void k_tail(
        const float* __restrict__ ghat, const float* __restrict__ Kp,
        const float* __restrict__ Vp,
        const float* __restrict__ wq, const float* __restrict__ bq,
        const float* __restrict__ wo, const float* __restrict__ bo,
        const float* __restrict__ p1w, const float* __restrict__ p1b,
        const float* __restrict__ lng, const float* __restrict__ lnb,
        float* __restrict__ tvec) {
    int b = blockIdx.x, t = threadIdx.x;
    int wvi = t >> 6, ln = t & 63;
    __shared__ float sq[128], sQ[128], sK[32][128], sV[32][128];
    __shared__ float sP[4][33], sO[128], sT[128], sZ[128];
    __shared__ float sred[2];
    __shared__ float sW[128 * 128];

#pragma unroll
    for (int s = 0; s < 4; s++) {
        int cb = s * 256 + wvi * 64;
        gload_lds16(Kp + (size_t)b * 4096 + (size_t)(cb + ln) * 4, (float*)sK + cb * 4);
        gload_lds16(Vp + (size_t)b * 4096 + (size_t)(cb + ln) * 4, (float*)sV + cb * 4);
    }
#pragma unroll
    for (int s = 0; s < 16; s++) {
        int cb = s * 256 + wvi * 64;
        gload_lds16(wq + (size_t)(cb + ln) * 4, &sW[cb * 4]);
    }
    if (t < 128) sq[t] = ghat[(size_t)b * 48 * 128 + t];
    __syncthreads();
    if (t < 128) {
        float a0 = 0.f, a1 = 0.f, a2 = 0.f, a3 = 0.f;
#pragma unroll
        for (int c = 0; c < 128; c += 4) {
            a0 += sq[c]     * sW[c * 128 + t];
            a1 += sq[c + 1] * sW[(c + 1) * 128 + t];
            a2 += sq[c + 2] * sW[(c + 2) * 128 + t];
            a3 += sq[c + 3] * sW[(c + 3) * 128 + t];
        }
        sQ[t] = bq[t] + ((a0 + a1) + (a2 + a3));
    }
    __syncthreads();
#pragma unroll
    for (int s = 0; s < 16; s++) {
        int cb = s * 256 + wvi * 64;
        gload_lds16(wo + (size_t)(cb + ln) * 4, &sW[cb * 4]);
    }
    if (t < 128) {
        int hh = t >> 5, jj = t & 31;
        float s = 0.f;
#pragma unroll
        for (int d = 0; d < 32; d++) s += sQ[hh * 32 + d] * sK[jj][hh * 32 + d];
        s *= 0.17677669529663687f;
        float m = s;
#pragma unroll
        for (int off = 16; off > 0; off >>= 1) m = fmaxf(m, __shfl_xor(m, off, 32));
        float p = __expf(s - m);
        float sum = p;
#pragma unroll
        for (int off = 16; off > 0; off >>= 1) sum += __shfl_xor(sum, off, 32);
        sP[hh][jj] = p / sum;
    }
    __syncthreads();
    if (t < 128) {
        int hh = t >> 5;
        float s = 0.f;
#pragma unroll
        for (int jj = 0; jj < 32; jj++) s += sP[hh][jj] * sV[jj][t];
        sO[t] = s;
    }
    __syncthreads();
    if (t < 128) {
        float a0 = 0.f, a1 = 0.f, a2 = 0.f, a3 = 0.f;
#pragma unroll
        for (int c = 0; c < 128; c += 4) {
            a0 += sO[c]     * sW[c * 128 + t];
            a1 += sO[c + 1] * sW[(c + 1) * 128 + t];
            a2 += sO[c + 2] * sW[(c + 2) * 128 + t];
            a3 += sO[c + 3] * sW[(c + 3) * 128 + t];
        }
        sT[t] = bo[t] + ((a0 + a1) + (a2 + a3));
    }
    __syncthreads();
#pragma unroll
    for (int s = 0; s < 16; s++) {
        int cb = s * 256 + wvi * 64;
        gload_lds16(p1w + (size_t)(cb + ln) * 4, &sW[cb * 4]);
    }
    __syncthreads();
    if (t < 128) {
        float a0 = 0.f, a1 = 0.f, a2 = 0.f, a3 = 0.f;
#pragma unroll
        for (int c = 0; c < 128; c += 4) {
            a0 += sT[c]     * sW[c * 128 + t];
            a1 += sT[c + 1] * sW[(c + 1) * 128 + t];
            a2 += sT[c + 2] * sW[(c + 2) * 128 + t];
            a3 += sT[c + 3] * sW[(c + 3) * 128 + t];
        }
        sZ[t] = p1b[t] + ((a0 + a1) + (a2 + a3));
    }
    __syncthreads();
    if (t < 64) {
        float v = sZ[t] + sZ[t + 64];
#pragma unroll
        for (int off = 32; off > 0; off >>= 1) v += __shfl_xor(v, off);
        if (t == 0) sred[0] = v * (1.f / 128.f);
    }
    __syncthreads();
    float mu = sred[0];
    if (t < 64) {
        float d1 = sZ[t] - mu, d2 = sZ[t + 64] - mu;
        float v = d1 * d1 + d2 * d2;
#pragma unroll
        for (int off = 32; off > 0; off >>= 1) v += __shfl_xor(v, off);
        if (t == 0) sred[1] = v * (1.f / 128.f);
    }
    __syncthreads();
    float rstd = rsqrtf(sred[1] + 1e-5f);
    if (t < 128) {
        float z = (sZ[t] - mu) * rstd * lng[t] + lnb[t];
        tvec[b * 128 + t] = fmaxf(z, 0.f);
    }
}

// ---------------- p2 projection: 48 blocks, gload_lds weight tiles -------------
__global__ __launch_bounds__(256) void k_p2(
        const float* __restrict__ tvec, const float* __restrict__ p2w,
        const float* __restrict__ p2b, float* __restrict__ out) {
    int jj0 = blockIdx.x * 128, b = blockIdx.y;
    int t = threadIdx.x, wvi = t >> 6, ln = t & 63;
    __shared__ float sT[128];
    __shared__ float sW[128 * 128];

#pragma unroll
    for (int s = 0; s < 16; s++) {
        int cb = s * 256 + wvi * 64;
        int q = cb + ln, c = q >> 5, c4 = q & 31;
        gload_lds16(p2w + (size_t)c * 768 + jj0 + c4 * 4, &sW[cb * 4]);
    }
    if (t < 128) sT[t] = tvec[b * 128 + t];
    __syncthreads();
    if (t < 128) {
        float a0 = 0.f, a1 = 0.f, a2 = 0.f, a3 = 0.f;
#pragma unroll
        for (int c = 0; c < 128; c += 4) {
            a0 += sT[c]     * sW[c * 128 + t];
            a1 += sT[c + 1] * sW[(c + 1) * 128 + t];
            a2 += sT[c + 2] * sW[(c + 2) * 128 + t];
            a3 += sT[c + 3] * sW[(c + 3) * 128 + t];
        }
        out[b * 768 + jj0 + t] = p2b[jj0 + t] + ((a0 + a1) + (a2 + a3));
    }
}

extern "C" void kernel_launch(void* const* d_in, const int* in_sizes, int n_in,
                              void* d_out, int out_size, void* d_ws, size_t ws_size,
                              hipStream_t stream) {
    const float* x   = (const float*)d_in[0];
    const int*  adj  = (const int*)d_in[1];
    const int*  cidx = (const int*)d_in[2];
    const float* W1  = (const float*)d_in[3];
    const float* a11 = (const float*)d_in[4];
    const float* a21 = (const float*)d_in[5];
    const float* W2  = (const float*)d_in[6];
    const float* a12 = (const float*)d_in[7];
    const float* a22 = (const float*)d_in[8];
    const float* wq = (const float*)d_in[9];  const float* bq = (const float*)d_in[10];
    const float* wk = (const float*)d_in[11]; const float* bk = (const float*)d_in[12];
    const float* wv = (const float*)d_in[13]; const float* bv = (const float*)d_in[14];
    const float* wo = (const float*)d_in[15]; const float* bo = (const float*)d_in[16];
    const float* p1w = (const float*)d_in[17]; const float* p1b = (const float*)d_in[18];
    const float* lng = (const float*)d_in[19]; const float* lnb = (const float*)d_in[20];
    const float* p2w = (const float*)d_in[21]; const float* p2b = (const float*)d_in[22];
    float* out = (float*)d_out;

    char* ws = (char*)d_ws;
    size_t off = 0;
    auto alloc = [&](size_t bytes) -> char* {
        char* p = ws + off;
        off = (off + bytes + 255) & ~(size_t)255;
        return p;
    };
    short* Xb   = (short*)alloc(8192ull * 768 * 2);
    short* W1T  = (short*)alloc(1024ull * 768 * 2);
    short* W2T  = (short*)alloc(128ull * 1024 * 2);
    unsigned* adjb = (unsigned*)alloc(8ull * 1024 * 32 * 4);
    short* h1t  = (short*)alloc(64ull * 128 * 1024 * 2);
    float* s1a  = (float*)alloc(64ull * 1024 * 4);
    float* s2a  = (float*)alloc(64ull * 1024 * 4);
    short* hcat = (short*)alloc(8192ull * 1024 * 2);
    short* h2t  = (short*)alloc(8ull * 128 * 1024 * 2);
    float* s1b  = (float*)alloc(8192ull * 4);
    float* s2b  = (float*)alloc(8192ull * 4);
    float* ghat = (float*)alloc(8ull * 48 * 128 * 4);
    float* Kp   = (float*)alloc(8ull * 32 * 128 * 4);
    float* Vp   = (float*)alloc(8ull * 32 * 128 * 4);
    float* tvec = (float*)alloc(8ull * 128 * 4);
    if (off > ws_size) return;

    // fused prep: adjbits | cast | w1t | w2t
    k_prep<<<42496, 256, 0, stream>>>(adj, adjb, x, Xb, W1, W1T, W2, W2T);

    // layer 1
    k_gemm_bt<<<dim3(64, 8), 256, 0, stream>>>(Xb, W1T, h1t, 768, 1024);
    k_s12<<<64, 256, 0, stream>>>(h1t, a11, a21, s1a, s2a, 8);
    k_attn1<<<dim3(8, 64), 512, 0, stream>>>(h1t, adjb, s1a, s2a, hcat);

    // layer 2 (GEMM full; attention only for gathered rows)
    k_gemm64<<<dim3(128, 2), 256, 0, stream>>>(hcat, W2T, h2t, 1024, 128);
    k_s12<<<8, 256, 0, stream>>>(h2t, a12, a22, s1b, s2b, 1);
    k_attn2g<<<dim3(3, 8), 256, 0, stream>>>(h2t, adjb, s1b, s2b, cidx, ghat);

    // tail
    k_qkv<<<dim3(16, 8), 256, 0, stream>>>(ghat, wk, bk, wv, bv, Kp, Vp);
    k_tail<<<8, 256, 0, stream>>>(ghat, Kp, Vp, wq, bq, wo, bo,
                                  p1w, p1b, lng, lnb, tvec);
    k_p2<<<dim3(6, 8), 256, 0, stream>>>(tvec, p2w, p2b, out);
}